// Round 2
// baseline (120.884 us; speedup 1.0000x reference)
//
#include <hip/hip_runtime.h>
#include <math.h>

#define N_ 4096
#define L_ 32
#define K_ 8
#define Dc_ 64
#define Db_ 64
#define Dd_ 16
#define C_ 8
#define B_ 32
#define M_ 1000
#define LOG2PI_ 1.8378770664093453f

// output layout (floats): [0]=-elbo [1]=LL [2]=KL_z [3]=KL_s
// [4 .. 4+N*K) = rik ; then term_1 (M), term_2 (M), term_3 (M)
#define OUT_RIK 4
#define OUT_T1 (4 + N_ * K_)

// d_ws layout (floats): [0..1000) ll_partial ; [1024..1536) inv_var[K][Dc] ; [1536..1544) const1[K]
#define WS_LLP 0
#define WS_IV 1024
#define WS_C1 1536

// ---------- prep: inv_var/const1 (block 0) + rik (blocks 1..64) ----------
__global__ __launch_bounds__(512) void mm_prep_kernel(
    const int* __restrict__ pidx, const float* __restrict__ qs_all,
    const float* __restrict__ lvg, float* __restrict__ out, float* __restrict__ ws)
{
    const int tid = threadIdx.x;
    if (blockIdx.x == 0) {
        // tid in [0,512) indexes (k = tid>>6, d = tid&63)
        float lv = lvg[tid];
        ws[WS_IV + tid] = __expf(-lv);
        float v = LOG2PI_ + lv;
        #pragma unroll
        for (int ofs = 1; ofs < 64; ofs <<= 1) v += __shfl_xor(v, ofs, 64);
        if ((tid & 63) == 0) ws[WS_C1 + (tid >> 6)] = v;
    } else {
        int i = (blockIdx.x - 1) * 512 + tid;   // [0, N*K)
        int r = i / K_, c = i % K_;
        int start = B_ * pidx[0];
        float v = 0.f;
        if (r >= start && r < start + B_) {
            const float* row = qs_all + (size_t)r * K_;
            float mx = row[0];
            #pragma unroll
            for (int j = 1; j < K_; ++j) mx = fmaxf(mx, row[j]);
            float se = 0.f;
            #pragma unroll
            for (int j = 0; j < K_; ++j) se += __expf(row[j] - mx);
            v = __expf(row[c] - mx) / se;
        }
        out[OUT_RIK + i] = v;
    }
}

// ---------- main: grid (500, 2); block 512 = 8 k-waves × (32 b × 2 m) ----------
__global__ __launch_bounds__(512, 8) void mm_main_kernel(
    const int* __restrict__ pidx,
    const float* __restrict__ Xc, const float* __restrict__ Xb, const int* __restrict__ Xd,
    const float* __restrict__ qm_all, const float* __restrict__ qlv_all, const float* __restrict__ qs_all,
    const float* __restrict__ Wg, const float* __restrict__ bg,
    const float* __restrict__ Wb, const float* __restrict__ bb,
    const float* __restrict__ Wd, const float* __restrict__ bd,
    const float* __restrict__ eps,
    float* __restrict__ out, float* __restrict__ ws)
{
    const int tid  = threadIdx.x;
    const int wave = tid >> 6;
    const int k    = __builtin_amdgcn_readfirstlane(wave);   // wave-uniform component index
    const int lane = tid & 63;
    const int b    = lane & 31;
    const int mo   = lane >> 5;
    const int m    = blockIdx.x * 2 + mo;
    const int half = blockIdx.y;                             // 0: t1+t2 ; 1: t3
    const int start = B_ * pidx[0];

    // ---- z[l] = qm + exp(0.5*qlv) * eps  (per (b,m); registers) ----
    float z[L_];
    {
        const float4* qm4 = reinterpret_cast<const float4*>(qm_all + (size_t)(start + b) * L_);
        const float4* ql4 = reinterpret_cast<const float4*>(qlv_all + (size_t)(start + b) * L_);
        const float4* ep4 = reinterpret_cast<const float4*>(eps + ((size_t)b * M_ + m) * L_);
        #pragma unroll
        for (int i = 0; i < L_ / 4; ++i) {
            float4 qm_v = qm4[i], ql_v = ql4[i], ep_v = ep4[i];
            z[i*4+0] = qm_v.x + __expf(0.5f * ql_v.x) * ep_v.x;
            z[i*4+1] = qm_v.y + __expf(0.5f * ql_v.y) * ep_v.y;
            z[i*4+2] = qm_v.z + __expf(0.5f * ql_v.z) * ep_v.z;
            z[i*4+3] = qm_v.w + __expf(0.5f * ql_v.w) * ep_v.w;
        }
    }

    float t1 = 0.f, t2 = 0.f, t3 = 0.f;

    if (half == 0) {
        // ---- Pass A: Gaussian term t1 (precomputed inv_var + const1) ----
        {
            const float* w   = Wg + (size_t)k * Dc_ * L_;
            const float* bgk = bg + k * Dc_;
            const float* ivk = ws + WS_IV + k * Dc_;
            const float* xcr = Xc + b * Dc_;
            float s = 0.f;
            #pragma unroll 2
            for (int d = 0; d < Dc_; ++d) {
                float acc = bgk[d];
                const float4* w4 = reinterpret_cast<const float4*>(w + d * L_);
                #pragma unroll
                for (int i = 0; i < L_ / 4; ++i) {
                    float4 wv = w4[i];
                    acc = fmaf(wv.x, z[i*4+0], acc);
                    acc = fmaf(wv.y, z[i*4+1], acc);
                    acc = fmaf(wv.z, z[i*4+2], acc);
                    acc = fmaf(wv.w, z[i*4+3], acc);
                }
                float diff = xcr[d] - acc;
                s = fmaf(diff * diff, ivk[d], s);
            }
            t1 = -0.5f * (ws[WS_C1 + k] + s);
        }
        // ---- Pass B: Bernoulli term t2 ----
        {
            const float* w   = Wb + (size_t)k * Db_ * L_;
            const float* bbk = bb + k * Db_;
            const float* xbr = Xb + b * Db_;
            #pragma unroll 2
            for (int d = 0; d < Db_; ++d) {
                float acc = bbk[d];
                const float4* w4 = reinterpret_cast<const float4*>(w + d * L_);
                #pragma unroll
                for (int i = 0; i < L_ / 4; ++i) {
                    float4 wv = w4[i];
                    acc = fmaf(wv.x, z[i*4+0], acc);
                    acc = fmaf(wv.y, z[i*4+1], acc);
                    acc = fmaf(wv.z, z[i*4+2], acc);
                    acc = fmaf(wv.w, z[i*4+3], acc);
                }
                // softplus(x) = max(x,0) + log(1+exp(-|x|))
                float sp = fmaxf(acc, 0.f) + __logf(1.f + __expf(-fabsf(acc)));
                t2 += xbr[d] * acc - sp;
            }
        }
    } else {
        // ---- Pass C: categorical term t3 ----
        const float* w   = Wd + (size_t)k * Dd_ * C_ * L_;
        const float* bdk = bd + k * Dd_ * C_;
        const int*   xdr = Xd + b * Dd_;
        #pragma unroll 1
        for (int d = 0; d < Dd_; ++d) {
            const float* wd0 = w + d * (C_ * L_);
            const float* bdd = bdk + d * C_;
            int xd = xdr[d];
            float lg[C_];
            #pragma unroll
            for (int c = 0; c < C_; ++c) {
                float acc = bdd[c];
                const float4* w4 = reinterpret_cast<const float4*>(wd0 + c * L_);
                #pragma unroll
                for (int i = 0; i < L_ / 4; ++i) {
                    float4 wv = w4[i];
                    acc = fmaf(wv.x, z[i*4+0], acc);
                    acc = fmaf(wv.y, z[i*4+1], acc);
                    acc = fmaf(wv.z, z[i*4+2], acc);
                    acc = fmaf(wv.w, z[i*4+3], acc);
                }
                lg[c] = acc;
            }
            float mx = lg[0];
            #pragma unroll
            for (int c = 1; c < C_; ++c) mx = fmaxf(mx, lg[c]);
            float se = 0.f;
            #pragma unroll
            for (int c = 0; c < C_; ++c) se += __expf(lg[c] - mx);
            float sel = lg[0];                       // gather via cndmask (no runtime array index)
            #pragma unroll
            for (int c = 1; c < C_; ++c) sel = (xd == c) ? lg[c] : sel;
            t3 += sel - mx - __logf(se);
        }
    }

    // ---- reductions ----
    float ll = qs_all[(size_t)(start + b) * K_ + k] * (t1 + t2 + t3);
    float r1 = t1, r2 = t2, r3 = t3;
    #pragma unroll
    for (int ofs = 1; ofs < 32; ofs <<= 1) {
        r1 += __shfl_xor(r1, ofs, 64);
        r2 += __shfl_xor(r2, ofs, 64);
        r3 += __shfl_xor(r3, ofs, 64);
        ll += __shfl_xor(ll, ofs, 64);
    }
    ll += __shfl_xor(ll, 32, 64);   // full-wave sum for LL

    __shared__ float red[8][2][3];
    __shared__ float llred[8];
    if (lane == 0)  { red[wave][0][0] = r1; red[wave][0][1] = r2; red[wave][0][2] = r3; llred[wave] = ll; }
    if (lane == 32) { red[wave][1][0] = r1; red[wave][1][1] = r2; red[wave][1][2] = r3; }
    __syncthreads();
    if (half == 0) {
        if (tid < 4) {
            int moi = tid >> 1, ti = tid & 1;
            float s = 0.f;
            #pragma unroll
            for (int w = 0; w < 8; ++w) s += red[w][moi][ti];
            out[OUT_T1 + ti * M_ + (blockIdx.x * 2 + moi)] = s;
        }
    } else {
        if (tid < 2) {
            float s = 0.f;
            #pragma unroll
            for (int w = 0; w < 8; ++w) s += red[w][tid][2];
            out[OUT_T1 + 2 * M_ + (blockIdx.x * 2 + tid)] = s;
        }
    }
    if (tid == 6) {
        float s = 0.f;
        #pragma unroll
        for (int w = 0; w < 8; ++w) s += llred[w];
        ws[WS_LLP + blockIdx.y * 500 + blockIdx.x] = s;
    }
}

__global__ void mm_final_kernel(const int* __restrict__ pidx,
                                const float* __restrict__ qm_all, const float* __restrict__ qlv_all,
                                const float* __restrict__ qs_all,
                                const float* __restrict__ pm_all, const float* __restrict__ pv_all,
                                const float* __restrict__ pmu_all,
                                const float* __restrict__ ll_partial, int nblk,
                                float* __restrict__ out)
{
    __shared__ float sdata[512];
    __shared__ float skl[B_], sks[B_];
    int t = threadIdx.x;
    int start = B_ * pidx[0];

    float v = 0.f;
    for (int i = t; i < nblk; i += 512) v += ll_partial[i];
    sdata[t] = v;

    if (t < B_) {
        int r = start + t;
        float kl = 0.f;
        for (int l = 0; l < L_; ++l) {
            float qmv = qm_all[(size_t)r * L_ + l];
            float qlv = qlv_all[(size_t)r * L_ + l];
            float mp  = pm_all[(size_t)r * L_ + l];
            float vp  = pv_all[(size_t)r * L_ + l];
            float d   = qmv - mp;
            kl += __logf(vp) - qlv + (__expf(qlv) + d * d) / vp - 1.f;
        }
        skl[t] = 0.5f * kl;

        float qsum = 0.f, psum = 0.f;
        #pragma unroll
        for (int j = 0; j < K_; ++j) { qsum += qs_all[(size_t)r * K_ + j]; psum += pmu_all[(size_t)r * K_ + j]; }
        float ks = 0.f;
        #pragma unroll
        for (int j = 0; j < K_; ++j) {
            float qn = qs_all[(size_t)r * K_ + j] / qsum;
            float pn = pmu_all[(size_t)r * K_ + j] / psum;
            ks += qn * (__logf(qn) - __logf(pn));
        }
        sks[t] = ks;
    }
    __syncthreads();
    if (t == 0) {
        float LL = 0.f;
        for (int i = 0; i < 512; ++i) LL += sdata[i];
        float sklz = 0.f, skls = 0.f;
        for (int i = 0; i < B_; ++i) { sklz += skl[i]; skls += sks[i]; }
        float elbo = LL - sklz - skls;
        out[0] = -elbo;
        out[1] = LL;
        out[2] = skl[B_ - 1];
        out[3] = sks[B_ - 1];
    }
}

extern "C" void kernel_launch(void* const* d_in, const int* in_sizes, int n_in,
                              void* d_out, int out_size, void* d_ws, size_t ws_size,
                              hipStream_t stream)
{
    (void)in_sizes; (void)n_in; (void)out_size; (void)ws_size;
    const int*   pidx = (const int*)d_in[0];
    const float* Xc   = (const float*)d_in[1];
    const float* Xb   = (const float*)d_in[2];
    const int*   Xd   = (const int*)d_in[3];
    const float* qm   = (const float*)d_in[4];
    const float* qlv  = (const float*)d_in[5];
    const float* qs   = (const float*)d_in[6];
    const float* pm   = (const float*)d_in[7];
    const float* pv   = (const float*)d_in[8];
    const float* pmu  = (const float*)d_in[9];
    const float* Wg   = (const float*)d_in[10];
    const float* bg   = (const float*)d_in[11];
    const float* lvg  = (const float*)d_in[12];
    const float* Wb   = (const float*)d_in[13];
    const float* bb   = (const float*)d_in[14];
    const float* Wd   = (const float*)d_in[15];
    const float* bd   = (const float*)d_in[16];
    const float* eps  = (const float*)d_in[17];
    float* out = (float*)d_out;
    float* ws  = (float*)d_ws;

    // prep: block 0 = inv_var/const1 ; blocks 1..64 = rik (N*K = 32768 = 64*512)
    mm_prep_kernel<<<65, 512, 0, stream>>>(pidx, qs, lvg, out, ws);

    dim3 grid(M_ / 2, 2);   // (500 m-pairs, 2 halves) -> 8000 waves
    mm_main_kernel<<<grid, 512, 0, stream>>>(pidx, Xc, Xb, Xd, qm, qlv, qs,
                                             Wg, bg, Wb, bb, Wd, bd, eps,
                                             out, ws);

    mm_final_kernel<<<1, 512, 0, stream>>>(pidx, qm, qlv, qs, pm, pv, pmu,
                                           ws + WS_LLP, 1000, out);
}

// Round 3
// 100.341 us; speedup vs baseline: 1.2047x; 1.2047x over previous
//
#include <hip/hip_runtime.h>
#include <math.h>

#define N_ 4096
#define L_ 32
#define K_ 8
#define Dc_ 64
#define Db_ 64
#define Dd_ 16
#define C_ 8
#define B_ 32
#define M_ 1000
#define LOG2PI_ 1.8378770664093453f

// output layout (floats): [0]=-elbo [1]=LL [2]=KL_z [3]=KL_s
// [4 .. 4+N*K) = rik ; then term_1 (M), term_2 (M), term_3 (M)
#define OUT_RIK 4
#define OUT_T1 (4 + N_ * K_)

// ws float-offsets
#define NBLK_MAIN (32 * 32 * 8)          // b*mtb*k = 8192 main blocks
#define WS_PART 0                        // 8192 * 128 floats
#define WS_WP   1048576                  // 65536 ushorts (32768 floats): bf16 weight frags
#define WS_BIAS (WS_WP + 32768)          // 2048 floats: bias per (k,col)
#define WS_IV   (WS_BIAS + 2048)         // 512 floats: exp(-logvar_g)
#define WS_C1   (WS_IV + 512)            // 8 floats
#define WS_ZF   (WS_C1 + 8)              // 1048576 ushorts (524288 floats): bf16 z frags

typedef __attribute__((ext_vector_type(8))) short short8v;
typedef __attribute__((ext_vector_type(4))) float f32x4;

__device__ inline unsigned short f2bf(float f) {
    unsigned u = __builtin_bit_cast(unsigned, f);
    unsigned r = u + 0x7FFFu + ((u >> 16) & 1u);   // round-to-nearest-even
    return (unsigned short)(r >> 16);
}

// ---------------- prep: z-frags, W-frags, bias/iv/c1, rik ----------------
#define PZ  1048576
#define PW  (PZ + 65536)
#define PB  (PW + 2048)
#define PIV (PB + 512)
#define PC1 (PIV + 8)
#define PRK (PC1 + N_ * K_)

__global__ __launch_bounds__(256) void mm_prep(
    const int* __restrict__ pidx, const float* __restrict__ qm_all,
    const float* __restrict__ qlv_all, const float* __restrict__ qs_all,
    const float* __restrict__ eps,
    const float* __restrict__ Wg, const float* __restrict__ bg, const float* __restrict__ lvg,
    const float* __restrict__ Wb, const float* __restrict__ bb,
    const float* __restrict__ Wd, const float* __restrict__ bd,
    float* __restrict__ out, float* __restrict__ ws)
{
    const long t = (long)blockIdx.x * 256 + threadIdx.x;
    unsigned short* zfw = (unsigned short*)(ws + WS_ZF);
    unsigned short* wpw = (unsigned short*)(ws + WS_WP);

    if (t < PZ) {
        // z fragment elem: [rt][lane][j] ; row = rt*16 + (lane&15); l = (lane>>4)*8 + j
        int j = (int)(t & 7), lane = (int)((t >> 3) & 63), rt = (int)(t >> 9);
        int row = rt * 16 + (lane & 15);
        int b = row >> 10, m = row & 1023;
        int l = (lane >> 4) * 8 + j;
        float z = 0.f;
        if (m < M_) {
            int start = B_ * pidx[0];
            z = qm_all[(size_t)(start + b) * L_ + l]
              + __expf(0.5f * qlv_all[(size_t)(start + b) * L_ + l])
              * eps[((size_t)b * M_ + m) * L_ + l];
        }
        zfw[t] = f2bf(z);
    } else if (t < PW) {
        // weight fragment elem: [k][ct][lane][j] ; col = ct*16+(lane&15); l = (lane>>4)*8+j
        long i = t - PZ;
        int j = (int)(i & 7), lane = (int)((i >> 3) & 63), ct = (int)((i >> 9) & 15), k = (int)(i >> 13);
        int col = ct * 16 + (lane & 15);
        int l = (lane >> 4) * 8 + j;
        float w;
        if (col < 64)       w = Wg[((size_t)k * 64 + col) * L_ + l];
        else if (col < 128) w = Wb[((size_t)k * 64 + (col - 64)) * L_ + l];
        else { int d = (col - 128) >> 3, c = col & 7; w = Wd[(((size_t)k * 16 + d) * 8 + c) * L_ + l]; }
        wpw[i] = f2bf(w);
    } else if (t < PB) {
        int i = (int)(t - PW); int k = i >> 8, col = i & 255;
        float v;
        if (col < 64)       v = bg[k * 64 + col];
        else if (col < 128) v = bb[k * 64 + col - 64];
        else { int d = (col - 128) >> 3, c = col & 7; v = bd[(k * 16 + d) * 8 + c]; }
        ws[WS_BIAS + i] = v;
    } else if (t < PIV) {
        int i = (int)(t - PB);
        ws[WS_IV + i] = __expf(-lvg[i]);
    } else if (t < PC1) {
        int k = (int)(t - PIV);
        float s = 0.f;
        for (int d = 0; d < 64; ++d) s += LOG2PI_ + lvg[k * 64 + d];
        ws[WS_C1 + k] = s;
    } else if (t < PRK) {
        long i = t - PC1;
        int r = (int)(i / K_), c = (int)(i % K_);
        int start = B_ * pidx[0];
        float v = 0.f;
        if (r >= start && r < start + B_) {
            const float* row = qs_all + (size_t)r * K_;
            float mx = row[0];
            #pragma unroll
            for (int jj = 1; jj < K_; ++jj) mx = fmaxf(mx, row[jj]);
            float se = 0.f;
            #pragma unroll
            for (int jj = 0; jj < K_; ++jj) se += __expf(row[jj] - mx);
            v = __expf(row[c] - mx) / se;
        }
        out[OUT_RIK + i] = v;
    }
}

// ---------------- main: grid (32 mtb, 32 b, 8 k), 256 threads = 4 waves ----------------
// wave handles 2 row-tiles x 4 col-tiles: ct = {w, 4+w, 8+2w, 9+2w}  (1 t1, 1 t2, 2 t3)
__global__ __launch_bounds__(256) void mm_main(
    const int* __restrict__ pidx,
    const float* __restrict__ Xc, const float* __restrict__ Xb, const int* __restrict__ Xd,
    const float* __restrict__ qs_all, float* __restrict__ ws)
{
    const int tid = threadIdx.x, wave = tid >> 6, lane = tid & 63;
    const int mtb = blockIdx.x, b = blockIdx.y, k = blockIdx.z;
    const int l15 = lane & 15, lg = lane >> 4;
    const unsigned short* zf = (const unsigned short*)(ws + WS_ZF);
    const unsigned short* wp = (const unsigned short*)(ws + WS_WP);

    const int rtg0 = b * 64 + mtb * 2;
    short8v a0 = *(const short8v*)(zf + (size_t)rtg0 * 512 + lane * 8);
    short8v a1 = *(const short8v*)(zf + ((size_t)rtg0 + 1) * 512 + lane * 8);

    float acc[3][2][4];
    #pragma unroll
    for (int tt = 0; tt < 3; ++tt)
        #pragma unroll
        for (int rt = 0; rt < 2; ++rt)
            #pragma unroll
            for (int j = 0; j < 4; ++j) acc[tt][rt][j] = 0.f;

    #pragma unroll
    for (int ct4 = 0; ct4 < 4; ++ct4) {
        const int ct = (ct4 == 0) ? wave : (ct4 == 1) ? (4 + wave) : (8 + 2 * wave + (ct4 - 2));
        short8v bf = *(const short8v*)(wp + ((size_t)(k * 16 + ct)) * 512 + lane * 8);
        f32x4 c0 = {0.f, 0.f, 0.f, 0.f}, c1v = {0.f, 0.f, 0.f, 0.f};
        c0  = __builtin_amdgcn_mfma_f32_16x16x32_bf16(a0, bf, c0, 0, 0, 0);
        c1v = __builtin_amdgcn_mfma_f32_16x16x32_bf16(a1, bf, c1v, 0, 0, 0);
        const int col = ct * 16 + l15;
        const float bias = ws[WS_BIAS + k * 256 + col];

        if (ct4 == 0) {          // t1 (Gaussian)
            const float xc = Xc[b * 64 + col];
            const float iv = ws[WS_IV + k * 64 + col];
            #pragma unroll
            for (int j = 0; j < 4; ++j) {
                float d0 = xc - (c0[j] + bias);  acc[0][0][j] = fmaf(d0 * d0, iv, acc[0][0][j]);
                float d1 = xc - (c1v[j] + bias); acc[0][1][j] = fmaf(d1 * d1, iv, acc[0][1][j]);
            }
        } else if (ct4 == 1) {   // t2 (Bernoulli)
            const float xb = Xb[b * 64 + (col - 64)];
            #pragma unroll
            for (int j = 0; j < 4; ++j) {
                { float lgt = c0[j] + bias;
                  float sp = fmaxf(lgt, 0.f) + __logf(1.f + __expf(-fabsf(lgt)));
                  acc[1][0][j] += xb * lgt - sp; }
                { float lgt = c1v[j] + bias;
                  float sp = fmaxf(lgt, 0.f) + __logf(1.f + __expf(-fabsf(lgt)));
                  acc[1][1][j] += xb * lgt - sp; }
            }
        } else {                 // t3 (categorical log-softmax, 8-lane groups)
            const int d = (col - 128) >> 3;
            const int xd = Xd[b * 16 + d];
            const float istar = ((col & 7) == xd) ? 1.f : 0.f;
            #pragma unroll
            for (int j = 0; j < 4; ++j) {
                { float lgt = c0[j] + bias;
                  float mx = lgt;
                  mx = fmaxf(mx, __shfl_xor(mx, 1, 64));
                  mx = fmaxf(mx, __shfl_xor(mx, 2, 64));
                  mx = fmaxf(mx, __shfl_xor(mx, 4, 64));
                  float e = __expf(lgt - mx);
                  float se = e;
                  se += __shfl_xor(se, 1, 64);
                  se += __shfl_xor(se, 2, 64);
                  se += __shfl_xor(se, 4, 64);
                  acc[2][0][j] += istar * (lgt - mx - __logf(se)); }
                { float lgt = c1v[j] + bias;
                  float mx = lgt;
                  mx = fmaxf(mx, __shfl_xor(mx, 1, 64));
                  mx = fmaxf(mx, __shfl_xor(mx, 2, 64));
                  mx = fmaxf(mx, __shfl_xor(mx, 4, 64));
                  float e = __expf(lgt - mx);
                  float se = e;
                  se += __shfl_xor(se, 1, 64);
                  se += __shfl_xor(se, 2, 64);
                  se += __shfl_xor(se, 4, 64);
                  acc[2][1][j] += istar * (lgt - mx - __logf(se)); }
            }
        }
    }

    // mask padded rows (m >= 1000)
    const int mrow_base = mtb * 32 + 4 * lg;
    #pragma unroll
    for (int j = 0; j < 4; ++j) {
        if (mrow_base + j >= M_) {
            #pragma unroll
            for (int tt = 0; tt < 3; ++tt) acc[tt][0][j] = 0.f;
        }
        if (mrow_base + 16 + j >= M_) {
            #pragma unroll
            for (int tt = 0; tt < 3; ++tt) acc[tt][1][j] = 0.f;
        }
    }

    // reduce across the 16 cols held by the 16 lanes of each row-group
    #pragma unroll
    for (int ofs = 1; ofs < 16; ofs <<= 1) {
        #pragma unroll
        for (int tt = 0; tt < 3; ++tt)
            #pragma unroll
            for (int rt = 0; rt < 2; ++rt)
                #pragma unroll
                for (int j = 0; j < 4; ++j)
                    acc[tt][rt][j] += __shfl_xor(acc[tt][rt][j], ofs, 64);
    }

    __shared__ float sred[4][3][2][16];
    __shared__ float srow[32];
    if (l15 == 0) {
        #pragma unroll
        for (int tt = 0; tt < 3; ++tt)
            #pragma unroll
            for (int rt = 0; rt < 2; ++rt)
                #pragma unroll
                for (int j = 0; j < 4; ++j)
                    sred[wave][tt][rt][4 * lg + j] = acc[tt][rt][j];
    }
    __syncthreads();

    const size_t pb = (((size_t)b * 32 + mtb) * 8 + k) * 128;
    if (tid < 32) {
        int rt = tid >> 4, row = tid & 15;
        float s1 = 0.f, s2 = 0.f, s3 = 0.f;
        #pragma unroll
        for (int w = 0; w < 4; ++w) {
            s1 += sred[w][0][rt][row];
            s2 += sred[w][1][rt][row];
            s3 += sred[w][2][rt][row];
        }
        float t1v = -0.5f * (ws[WS_C1 + k] + s1);
        int m = mtb * 32 + tid;
        if (m >= M_) { t1v = 0.f; s2 = 0.f; s3 = 0.f; }
        ws[WS_PART + pb + tid]      = t1v;
        ws[WS_PART + pb + 32 + tid] = s2;
        ws[WS_PART + pb + 64 + tid] = s3;
        srow[tid] = t1v + s2 + s3;
    }
    __syncthreads();
    if (tid == 0) {
        float s = 0.f;
        #pragma unroll
        for (int i = 0; i < 32; ++i) s += srow[i];
        int start = B_ * pidx[0];
        ws[WS_PART + pb + 96] = qs_all[(size_t)(start + b) * K_ + k] * s;
    }
}

// ---------------- final: block 0 = LL/KL/elbo ; blocks 1..12 = term_i[m] ----------------
__global__ __launch_bounds__(256) void mm_final(
    const int* __restrict__ pidx,
    const float* __restrict__ qm_all, const float* __restrict__ qlv_all,
    const float* __restrict__ qs_all,
    const float* __restrict__ pm_all, const float* __restrict__ pv_all,
    const float* __restrict__ pmu_all,
    const float* __restrict__ ws, float* __restrict__ out)
{
    const int tid = threadIdx.x;
    if (blockIdx.x == 0) {
        __shared__ float sdata[256];
        __shared__ float skl[B_], sks[B_];
        const int start = B_ * pidx[0];
        float v = 0.f;
        for (int i = tid; i < NBLK_MAIN; i += 256) v += ws[WS_PART + (size_t)i * 128 + 96];
        sdata[tid] = v;

        if (tid < B_) {
            int r = start + tid;
            float kl = 0.f;
            for (int l = 0; l < L_; ++l) {
                float qmv = qm_all[(size_t)r * L_ + l];
                float qlv = qlv_all[(size_t)r * L_ + l];
                float mp  = pm_all[(size_t)r * L_ + l];
                float vp  = pv_all[(size_t)r * L_ + l];
                float d   = qmv - mp;
                kl += __logf(vp) - qlv + (__expf(qlv) + d * d) / vp - 1.f;
            }
            skl[tid] = 0.5f * kl;

            float qsum = 0.f, psum = 0.f;
            #pragma unroll
            for (int j = 0; j < K_; ++j) {
                qsum += qs_all[(size_t)r * K_ + j];
                psum += pmu_all[(size_t)r * K_ + j];
            }
            float ks = 0.f;
            #pragma unroll
            for (int j = 0; j < K_; ++j) {
                float qn = qs_all[(size_t)r * K_ + j] / qsum;
                float pn = pmu_all[(size_t)r * K_ + j] / psum;
                ks += qn * (__logf(qn) - __logf(pn));
            }
            sks[tid] = ks;
        }
        __syncthreads();
        if (tid == 0) {
            float LL = 0.f;
            for (int i = 0; i < 256; ++i) LL += sdata[i];
            float sklz = 0.f, skls = 0.f;
            for (int i = 0; i < B_; ++i) { sklz += skl[i]; skls += sks[i]; }
            float elbo = LL - sklz - skls;
            out[0] = -elbo;
            out[1] = LL;
            out[2] = skl[B_ - 1];
            out[3] = sks[B_ - 1];
        }
    } else {
        int g = (blockIdx.x - 1) * 256 + tid;
        if (g < 3 * M_) {
            int i = g / M_, m = g % M_;
            int mt = m >> 5, row = m & 31;
            float s = 0.f;
            for (int b2 = 0; b2 < 32; ++b2)
                for (int kk = 0; kk < 8; ++kk)
                    s += ws[WS_PART + (((size_t)b2 * 32 + mt) * 8 + kk) * 128 + i * 32 + row];
            out[OUT_T1 + i * M_ + m] = s;
        }
    }
}

extern "C" void kernel_launch(void* const* d_in, const int* in_sizes, int n_in,
                              void* d_out, int out_size, void* d_ws, size_t ws_size,
                              hipStream_t stream)
{
    (void)in_sizes; (void)n_in; (void)out_size; (void)ws_size;
    const int*   pidx = (const int*)d_in[0];
    const float* Xc   = (const float*)d_in[1];
    const float* Xb   = (const float*)d_in[2];
    const int*   Xd   = (const int*)d_in[3];
    const float* qm   = (const float*)d_in[4];
    const float* qlv  = (const float*)d_in[5];
    const float* qs   = (const float*)d_in[6];
    const float* pm   = (const float*)d_in[7];
    const float* pv   = (const float*)d_in[8];
    const float* pmu  = (const float*)d_in[9];
    const float* Wg   = (const float*)d_in[10];
    const float* bg   = (const float*)d_in[11];
    const float* lvg  = (const float*)d_in[12];
    const float* Wb   = (const float*)d_in[13];
    const float* bb   = (const float*)d_in[14];
    const float* Wd   = (const float*)d_in[15];
    const float* bd   = (const float*)d_in[16];
    const float* eps  = (const float*)d_in[17];
    float* out = (float*)d_out;
    float* ws  = (float*)d_ws;

    mm_prep<<<(PRK + 255) / 256, 256, 0, stream>>>(pidx, qm, qlv, qs, eps,
                                                   Wg, bg, lvg, Wb, bb, Wd, bd,
                                                   out, ws);

    dim3 grid(32, 32, 8);   // (mtb, b, k)
    mm_main<<<grid, 256, 0, stream>>>(pidx, Xc, Xb, Xd, qs, ws);

    mm_final<<<13, 256, 0, stream>>>(pidx, qm, qlv, qs, pm, pv, pmu, ws, out);
}

// Round 4
// 62.698 us; speedup vs baseline: 1.9280x; 1.6004x over previous
//
#include <hip/hip_runtime.h>
#include <math.h>

#define N_ 4096
#define L_ 32
#define K_ 8
#define Dc_ 64
#define Db_ 64
#define Dd_ 16
#define C_ 8
#define B_ 32
#define M_ 1000
#define LOG2PI_ 1.8378770664093453f

// output layout (floats): [0]=-elbo [1]=LL [2]=KL_z [3]=KL_s
// [4 .. 4+N*K) = rik ; then term_1 (M), term_2 (M), term_3 (M)
#define OUT_RIK 4
#define OUT_T1 (4 + N_ * K_)

// ws float-offsets
#define WS_PART 0                         // 256*63*48 = 774144 floats: per (b,k,mt) 3x16
#define WS_LLP  774144                    // 2304 floats: per-block LL partials
#define WS_WP   776448                    // 65536 ushorts (32768 floats): bf16 weight frags
#define WS_BIAS (WS_WP + 32768)           // 2048 floats
#define WS_IV   (WS_BIAS + 2048)          // 512 floats
#define WS_C1   (WS_IV + 512)             // 8 floats
#define WS_ZF   (WS_C1 + 8)               // 1048576 ushorts (524288 floats): bf16 z frags

typedef __attribute__((ext_vector_type(8))) short short8v;
typedef __attribute__((ext_vector_type(4))) float f32x4;

__device__ inline unsigned short f2bf(float f) {
    unsigned u = __builtin_bit_cast(unsigned, f);
    unsigned r = u + 0x7FFFu + ((u >> 16) & 1u);   // round-to-nearest-even
    return (unsigned short)(r >> 16);
}

// ---------------- prep: z-frags, W-frags, bias/iv/c1, rik ----------------
#define PZ  1048576
#define PW  (PZ + 65536)
#define PB  (PW + 2048)
#define PIV (PB + 512)
#define PC1 (PIV + 8)
#define PRK (PC1 + N_ * K_)

__global__ __launch_bounds__(256) void mm_prep(
    const int* __restrict__ pidx, const float* __restrict__ qm_all,
    const float* __restrict__ qlv_all, const float* __restrict__ qs_all,
    const float* __restrict__ eps,
    const float* __restrict__ Wg, const float* __restrict__ bg, const float* __restrict__ lvg,
    const float* __restrict__ Wb, const float* __restrict__ bb,
    const float* __restrict__ Wd, const float* __restrict__ bd,
    float* __restrict__ out, float* __restrict__ ws)
{
    const long t = (long)blockIdx.x * 256 + threadIdx.x;
    unsigned short* zfw = (unsigned short*)(ws + WS_ZF);
    unsigned short* wpw = (unsigned short*)(ws + WS_WP);

    if (t < PZ) {
        // z fragment elem: [rt][lane][j] ; m-row = rt*16 + (lane&15); l = (lane>>4)*8 + j
        int j = (int)(t & 7), lane = (int)((t >> 3) & 63), rt = (int)(t >> 9);
        int row = rt * 16 + (lane & 15);
        int b = row >> 10, m = row & 1023;
        int l = (lane >> 4) * 8 + j;
        float z = 0.f;
        if (m < M_) {
            int start = B_ * pidx[0];
            z = qm_all[(size_t)(start + b) * L_ + l]
              + __expf(0.5f * qlv_all[(size_t)(start + b) * L_ + l])
              * eps[((size_t)b * M_ + m) * L_ + l];
        }
        zfw[t] = f2bf(z);
    } else if (t < PW) {
        // weight fragment elem: [k][ft][lane][j] ; feature = ft*16+(lane&15); l = (lane>>4)*8+j
        long i = t - PZ;
        int j = (int)(i & 7), lane = (int)((i >> 3) & 63), ft = (int)((i >> 9) & 15), k = (int)(i >> 13);
        int f = ft * 16 + (lane & 15);
        int l = (lane >> 4) * 8 + j;
        float w;
        if (f < 64)       w = Wg[((size_t)k * 64 + f) * L_ + l];
        else if (f < 128) w = Wb[((size_t)k * 64 + (f - 64)) * L_ + l];
        else { int d = (f - 128) >> 3, c = f & 7; w = Wd[(((size_t)k * 16 + d) * 8 + c) * L_ + l]; }
        wpw[i] = f2bf(w);
    } else if (t < PB) {
        int i = (int)(t - PW); int k = i >> 8, f = i & 255;
        float v;
        if (f < 64)       v = bg[k * 64 + f];
        else if (f < 128) v = bb[k * 64 + f - 64];
        else { int d = (f - 128) >> 3, c = f & 7; v = bd[(k * 16 + d) * 8 + c]; }
        ws[WS_BIAS + i] = v;
    } else if (t < PIV) {
        int i = (int)(t - PB);
        ws[WS_IV + i] = __expf(-lvg[i]);
    } else if (t < PC1) {
        int k = (int)(t - PIV);
        float s = 0.f;
        for (int d = 0; d < 64; ++d) s += LOG2PI_ + lvg[k * 64 + d];
        ws[WS_C1 + k] = s;
    } else if (t < PRK) {
        long i = t - PC1;
        int r = (int)(i / K_), c = (int)(i % K_);
        int start = B_ * pidx[0];
        float v = 0.f;
        if (r >= start && r < start + B_) {
            const float* row = qs_all + (size_t)r * K_;
            float mx = row[0];
            #pragma unroll
            for (int jj = 1; jj < K_; ++jj) mx = fmaxf(mx, row[jj]);
            float se = 0.f;
            #pragma unroll
            for (int jj = 0; jj < K_; ++jj) se += __expf(row[jj] - mx);
            v = __expf(row[c] - mx) / se;
        }
        out[OUT_RIK + i] = v;
    }
}

// ---------------- main: grid (9 chunks, 32 b, 8 k); 256 thr = 4 waves ----------------
// Transposed MFMA: A = weight frag (rows = features), B = z frag (cols = m-rows).
// Wave w owns feature-tiles {w, 4+w, 8+w, 12+w} = 1 t1, 1 t2, 2 t3 tiles; loops 7 m-tiles.
__global__ __launch_bounds__(256) void mm_main(
    const int* __restrict__ pidx,
    const float* __restrict__ Xc, const float* __restrict__ Xb, const int* __restrict__ Xd,
    const float* __restrict__ qs_all, float* __restrict__ ws)
{
    const int tid = threadIdx.x, w = tid >> 6, lane = tid & 63;
    const int chunk = blockIdx.x, b = blockIdx.y, k = blockIdx.z;
    const int l15 = lane & 15, lg = lane >> 4;
    const unsigned short* zf = (const unsigned short*)(ws + WS_ZF);
    const unsigned short* wp = (const unsigned short*)(ws + WS_WP);

    // hoisted weight fragments
    short8v aA = *(const short8v*)(wp + ((size_t)(k * 16 + w))      * 512 + lane * 8);
    short8v aB = *(const short8v*)(wp + ((size_t)(k * 16 + 4 + w))  * 512 + lane * 8);
    short8v aC = *(const short8v*)(wp + ((size_t)(k * 16 + 8 + w))  * 512 + lane * 8);
    short8v aD = *(const short8v*)(wp + ((size_t)(k * 16 + 12 + w)) * 512 + lane * 8);

    // hoisted per-feature constants (feature = ft*16 + 4*lg + j)
    const int fr = 4 * lg;
    const float4 biasA = *(const float4*)(ws + WS_BIAS + k * 256 + w * 16 + fr);
    const float4 biasB = *(const float4*)(ws + WS_BIAS + k * 256 + (4 + w) * 16 + fr);
    const float4 biasC = *(const float4*)(ws + WS_BIAS + k * 256 + (8 + w) * 16 + fr);
    const float4 biasD = *(const float4*)(ws + WS_BIAS + k * 256 + (12 + w) * 16 + fr);
    const float4 xcA = *(const float4*)(Xc + b * 64 + w * 16 + fr);
    const float4 ivA = *(const float4*)(ws + WS_IV + k * 64 + w * 16 + fr);
    const float4 xbB = *(const float4*)(Xb + b * 64 + w * 16 + fr);
    const int dC = 2 * w + (lg >> 1);
    const int dD = 8 + 2 * w + (lg >> 1);
    const int xdC = Xd[b * 16 + dC], xdD = Xd[b * 16 + dD];
    const int c0 = 4 * (lg & 1);
    float4 isC, isD;
    isC.x = (c0 + 0 == xdC) ? 1.f : 0.f;  isC.y = (c0 + 1 == xdC) ? 1.f : 0.f;
    isC.z = (c0 + 2 == xdC) ? 1.f : 0.f;  isC.w = (c0 + 3 == xdC) ? 1.f : 0.f;
    isD.x = (c0 + 0 == xdD) ? 1.f : 0.f;  isD.y = (c0 + 1 == xdD) ? 1.f : 0.f;
    isD.z = (c0 + 2 == xdD) ? 1.f : 0.f;  isD.w = (c0 + 3 == xdD) ? 1.f : 0.f;
    const float c1k = (w == 0) ? ws[WS_C1 + k] : 0.f;   // add const1 once per (m,k)

    __shared__ float sred[4][3][16];
    __shared__ float llred[4];
    float ll = 0.f;
    const size_t pbase = (size_t)(b * 8 + k) * 63;

    short8v zb = *(const short8v*)(zf + ((size_t)(b * 64 + chunk * 7)) * 512 + lane * 8);
    for (int it = 0; it < 7; ++it) {
        const int mt = chunk * 7 + it;
        short8v zn = zb;
        if (it < 6) zn = *(const short8v*)(zf + ((size_t)(b * 64 + mt + 1)) * 512 + lane * 8);

        f32x4 c;
        // ---- t1 (Gaussian) ----
        c = (f32x4){0.f, 0.f, 0.f, 0.f};
        c = __builtin_amdgcn_mfma_f32_16x16x32_bf16(aA, zb, c, 0, 0, 0);
        float r1 = 0.f;
        { float d0;
          d0 = xcA.x - (c[0] + biasA.x); r1 = fmaf(d0 * d0, ivA.x, r1);
          d0 = xcA.y - (c[1] + biasA.y); r1 = fmaf(d0 * d0, ivA.y, r1);
          d0 = xcA.z - (c[2] + biasA.z); r1 = fmaf(d0 * d0, ivA.z, r1);
          d0 = xcA.w - (c[3] + biasA.w); r1 = fmaf(d0 * d0, ivA.w, r1); }
        // ---- t2 (Bernoulli) ----
        c = (f32x4){0.f, 0.f, 0.f, 0.f};
        c = __builtin_amdgcn_mfma_f32_16x16x32_bf16(aB, zb, c, 0, 0, 0);
        float r2 = 0.f;
        { float lgt, sp;
          lgt = c[0] + biasB.x; sp = fmaxf(lgt, 0.f) + __logf(1.f + __expf(-fabsf(lgt))); r2 += xbB.x * lgt - sp;
          lgt = c[1] + biasB.y; sp = fmaxf(lgt, 0.f) + __logf(1.f + __expf(-fabsf(lgt))); r2 += xbB.y * lgt - sp;
          lgt = c[2] + biasB.z; sp = fmaxf(lgt, 0.f) + __logf(1.f + __expf(-fabsf(lgt))); r2 += xbB.z * lgt - sp;
          lgt = c[3] + biasB.w; sp = fmaxf(lgt, 0.f) + __logf(1.f + __expf(-fabsf(lgt))); r2 += xbB.w * lgt - sp; }
        // ---- t3 tile C ----
        float r3;
        c = (f32x4){0.f, 0.f, 0.f, 0.f};
        c = __builtin_amdgcn_mfma_f32_16x16x32_bf16(aC, zb, c, 0, 0, 0);
        { float l0 = c[0] + biasC.x, l1 = c[1] + biasC.y, l2 = c[2] + biasC.z, l3 = c[3] + biasC.w;
          float mx = fmaxf(fmaxf(l0, l1), fmaxf(l2, l3));
          mx = fmaxf(mx, __shfl_xor(mx, 16, 64));
          float e = __expf(l0 - mx) + __expf(l1 - mx) + __expf(l2 - mx) + __expf(l3 - mx);
          e += __shfl_xor(e, 16, 64);
          float pk = isC.x * l0 + isC.y * l1 + isC.z * l2 + isC.w * l3;
          pk += __shfl_xor(pk, 16, 64);
          r3 = pk - mx - __logf(e); }
        // ---- t3 tile D ----
        c = (f32x4){0.f, 0.f, 0.f, 0.f};
        c = __builtin_amdgcn_mfma_f32_16x16x32_bf16(aD, zb, c, 0, 0, 0);
        { float l0 = c[0] + biasD.x, l1 = c[1] + biasD.y, l2 = c[2] + biasD.z, l3 = c[3] + biasD.w;
          float mx = fmaxf(fmaxf(l0, l1), fmaxf(l2, l3));
          mx = fmaxf(mx, __shfl_xor(mx, 16, 64));
          float e = __expf(l0 - mx) + __expf(l1 - mx) + __expf(l2 - mx) + __expf(l3 - mx);
          e += __shfl_xor(e, 16, 64);
          float pk = isD.x * l0 + isD.y * l1 + isD.z * l2 + isD.w * l3;
          pk += __shfl_xor(pk, 16, 64);
          r3 += pk - mx - __logf(e); }

        // ---- reduce over lane-groups (features of this wave) ----
        r1 += __shfl_xor(r1, 16, 64); r1 += __shfl_xor(r1, 32, 64);
        r2 += __shfl_xor(r2, 16, 64); r2 += __shfl_xor(r2, 32, 64);
        r3 += __shfl_xor(r3, 16, 64); r3 += __shfl_xor(r3, 32, 64);
        r3 *= 0.5f;                            // t3 values duplicated on xor16 pairs
        r1 = -0.5f * (c1k + r1);               // Gaussian scale + const (wave 0 only)

        const int m = mt * 16 + l15;
        if (m >= M_) { r1 = 0.f; r2 = 0.f; r3 = 0.f; }
        ll += r1 + r2 + r3;

        if (lane < 16) { sred[w][0][l15] = r1; sred[w][1][l15] = r2; sred[w][2][l15] = r3; }
        __syncthreads();
        if (tid < 48) {
            int i = tid >> 4, cx = tid & 15;
            float s = sred[0][i][cx] + sred[1][i][cx] + sred[2][i][cx] + sred[3][i][cx];
            ws[WS_PART + (pbase + mt) * 48 + tid] = s;
        }
        __syncthreads();
        zb = zn;
    }

    // ---- LL partial (per block) ----
    ll += __shfl_xor(ll, 1, 64); ll += __shfl_xor(ll, 2, 64);
    ll += __shfl_xor(ll, 4, 64); ll += __shfl_xor(ll, 8, 64);
    if (lane == 0) llred[w] = ll;
    __syncthreads();
    if (tid == 0) {
        int start = B_ * pidx[0];
        float s = llred[0] + llred[1] + llred[2] + llred[3];
        ws[WS_LLP + (size_t)(k * 32 + b) * 9 + chunk] = qs_all[(size_t)(start + b) * K_ + k] * s;
    }
}

// ---------------- final: block 0 = LL/KL/elbo ; blocks 1..12 = term_i[m] ----------------
__global__ __launch_bounds__(256) void mm_final(
    const int* __restrict__ pidx,
    const float* __restrict__ qm_all, const float* __restrict__ qlv_all,
    const float* __restrict__ qs_all,
    const float* __restrict__ pm_all, const float* __restrict__ pv_all,
    const float* __restrict__ pmu_all,
    const float* __restrict__ ws, float* __restrict__ out)
{
    const int tid = threadIdx.x;
    if (blockIdx.x == 0) {
        __shared__ float sdata[256];
        __shared__ float skl[B_], sks[B_];
        const int start = B_ * pidx[0];
        float v = 0.f;
        for (int i = tid; i < 2304; i += 256) v += ws[WS_LLP + i];
        sdata[tid] = v;

        if (tid < B_) {
            int r = start + tid;
            float kl = 0.f;
            for (int l = 0; l < L_; ++l) {
                float qmv = qm_all[(size_t)r * L_ + l];
                float qlv = qlv_all[(size_t)r * L_ + l];
                float mp  = pm_all[(size_t)r * L_ + l];
                float vp  = pv_all[(size_t)r * L_ + l];
                float d   = qmv - mp;
                kl += __logf(vp) - qlv + (__expf(qlv) + d * d) / vp - 1.f;
            }
            skl[tid] = 0.5f * kl;

            float qsum = 0.f, psum = 0.f;
            #pragma unroll
            for (int j = 0; j < K_; ++j) {
                qsum += qs_all[(size_t)r * K_ + j];
                psum += pmu_all[(size_t)r * K_ + j];
            }
            float ks = 0.f;
            #pragma unroll
            for (int j = 0; j < K_; ++j) {
                float qn = qs_all[(size_t)r * K_ + j] / qsum;
                float pn = pmu_all[(size_t)r * K_ + j] / psum;
                ks += qn * (__logf(qn) - __logf(pn));
            }
            sks[tid] = ks;
        }
        __syncthreads();
        if (tid == 0) {
            float LL = 0.f;
            for (int i = 0; i < 256; ++i) LL += sdata[i];
            float sklz = 0.f, skls = 0.f;
            for (int i = 0; i < B_; ++i) { sklz += skl[i]; skls += sks[i]; }
            float elbo = LL - sklz - skls;
            out[0] = -elbo;
            out[1] = LL;
            out[2] = skl[B_ - 1];
            out[3] = sks[B_ - 1];
        }
    } else {
        int g = (blockIdx.x - 1) * 256 + tid;
        if (g < 3 * M_) {
            int i = g / M_, m = g % M_;
            int mt = m >> 4, cx = m & 15;
            float s = 0.f;
            for (int bk = 0; bk < 256; ++bk)
                s += ws[WS_PART + ((size_t)bk * 63 + mt) * 48 + i * 16 + cx];
            out[OUT_T1 + i * M_ + m] = s;
        }
    }
}

extern "C" void kernel_launch(void* const* d_in, const int* in_sizes, int n_in,
                              void* d_out, int out_size, void* d_ws, size_t ws_size,
                              hipStream_t stream)
{
    (void)in_sizes; (void)n_in; (void)out_size; (void)ws_size;
    const int*   pidx = (const int*)d_in[0];
    const float* Xc   = (const float*)d_in[1];
    const float* Xb   = (const float*)d_in[2];
    const int*   Xd   = (const int*)d_in[3];
    const float* qm   = (const float*)d_in[4];
    const float* qlv  = (const float*)d_in[5];
    const float* qs   = (const float*)d_in[6];
    const float* pm   = (const float*)d_in[7];
    const float* pv   = (const float*)d_in[8];
    const float* pmu  = (const float*)d_in[9];
    const float* Wg   = (const float*)d_in[10];
    const float* bg   = (const float*)d_in[11];
    const float* lvg  = (const float*)d_in[12];
    const float* Wb   = (const float*)d_in[13];
    const float* bb   = (const float*)d_in[14];
    const float* Wd   = (const float*)d_in[15];
    const float* bd   = (const float*)d_in[16];
    const float* eps  = (const float*)d_in[17];
    float* out = (float*)d_out;
    float* ws  = (float*)d_ws;

    mm_prep<<<(PRK + 255) / 256, 256, 0, stream>>>(pidx, qm, qlv, qs, eps,
                                                   Wg, bg, lvg, Wb, bb, Wd, bd,
                                                   out, ws);

    dim3 grid(9, 32, 8);   // (m-chunk, b, k)
    mm_main<<<grid, 256, 0, stream>>>(pidx, Xc, Xb, Xd, qs, ws);

    mm_final<<<13, 256, 0, stream>>>(pidx, qm, qlv, qs, pm, pv, pmu, ws, out);
}

// Round 5
// 52.457 us; speedup vs baseline: 2.3045x; 1.1952x over previous
//
#include <hip/hip_runtime.h>
#include <math.h>

#define N_ 4096
#define L_ 32
#define K_ 8
#define Dc_ 64
#define Db_ 64
#define Dd_ 16
#define C_ 8
#define B_ 32
#define M_ 1000
#define LOG2PI_ 1.8378770664093453f

// output layout (floats): [0]=-elbo [1]=LL [2]=KL_z [3]=KL_s
// [4 .. 4+N*K) = rik ; then term_1 (M), term_2 (M), term_3 (M)
#define OUT_RIK 4
#define OUT_T1 (4 + N_ * K_)

// ws float-offsets
#define WS_PART 0                 // 32*63*48 = 96768 floats: per (b,mt) 3x16 (k-summed)
#define WS_LLP  98304             // 672 floats: per-block LL partials (32 b * 21 chunks)
#define WS_WP   100352            // 65536 ushorts (32768 floats): bf16 weight frags
#define WS_BIAS (WS_WP + 32768)   // 2048 floats
#define WS_IV   (WS_BIAS + 2048)  // 512 floats
#define WS_C1   (WS_IV + 512)     // 8 floats

typedef __attribute__((ext_vector_type(8))) short short8v;
typedef __attribute__((ext_vector_type(4))) float f32x4;

__device__ inline unsigned short f2bf(float f) {
    unsigned u = __builtin_bit_cast(unsigned, f);
    unsigned r = u + 0x7FFFu + ((u >> 16) & 1u);   // round-to-nearest-even
    return (unsigned short)(r >> 16);
}

// ---------------- prep: W-frags, bias/iv/c1, rik ----------------
#define PW  65536
#define PB  (PW + 2048)
#define PIV (PB + 512)
#define PC1 (PIV + 8)
#define PRK (PC1 + N_ * K_)

__global__ __launch_bounds__(256) void mm_prep(
    const int* __restrict__ pidx, const float* __restrict__ qs_all,
    const float* __restrict__ Wg, const float* __restrict__ bg, const float* __restrict__ lvg,
    const float* __restrict__ Wb, const float* __restrict__ bb,
    const float* __restrict__ Wd, const float* __restrict__ bd,
    float* __restrict__ out, float* __restrict__ ws)
{
    const int t = blockIdx.x * 256 + threadIdx.x;
    unsigned short* wpw = (unsigned short*)(ws + WS_WP);

    if (t < PW) {
        // weight fragment elem: [k][ft][lane][j] ; feature = ft*16+(lane&15); l = (lane>>4)*8+j
        int j = t & 7, lane = (t >> 3) & 63, ft = (t >> 9) & 15, k = t >> 13;
        int f = ft * 16 + (lane & 15);
        int l = (lane >> 4) * 8 + j;
        float w;
        if (f < 64)       w = Wg[((size_t)k * 64 + f) * L_ + l];
        else if (f < 128) w = Wb[((size_t)k * 64 + (f - 64)) * L_ + l];
        else { int d = (f - 128) >> 3, c = f & 7; w = Wd[(((size_t)k * 16 + d) * 8 + c) * L_ + l]; }
        wpw[t] = f2bf(w);
    } else if (t < PB) {
        int i = t - PW; int k = i >> 8, f = i & 255;
        float v;
        if (f < 64)       v = bg[k * 64 + f];
        else if (f < 128) v = bb[k * 64 + f - 64];
        else { int d = (f - 128) >> 3, c = f & 7; v = bd[(k * 16 + d) * 8 + c]; }
        ws[WS_BIAS + i] = v;
    } else if (t < PIV) {
        int i = t - PB;
        ws[WS_IV + i] = __expf(-lvg[i]);
    } else if (t < PC1) {
        int k = t - PIV;
        float s = 0.f;
        for (int d = 0; d < 64; ++d) s += LOG2PI_ + lvg[k * 64 + d];
        ws[WS_C1 + k] = s;
    } else if (t < PRK) {
        int i = t - PC1;
        int r = i / K_, c = i % K_;
        int start = B_ * pidx[0];
        float v = 0.f;
        if (r >= start && r < start + B_) {
            const float* row = qs_all + (size_t)r * K_;
            float mx = row[0];
            #pragma unroll
            for (int jj = 1; jj < K_; ++jj) mx = fmaxf(mx, row[jj]);
            float se = 0.f;
            #pragma unroll
            for (int jj = 0; jj < K_; ++jj) se += __expf(row[jj] - mx);
            v = __expf(row[c] - mx) / se;
        }
        out[OUT_RIK + i] = v;
    }
}

// ---------------- main: grid (21 chunks, 32 b); 512 thr = 8 waves ----------------
// Fused z-staging (LDS) + transposed MFMA + k-loop with register accumulation.
// Wave w owns feature-tiles {w, 8+w}: w<4 -> (t1 tile, t3 tile); w>=4 -> (t2 tile, t3 tile).
__global__ __launch_bounds__(512) void mm_main(
    const int* __restrict__ pidx,
    const float* __restrict__ Xc, const float* __restrict__ Xb, const int* __restrict__ Xd,
    const float* __restrict__ qm_all, const float* __restrict__ qlv_all,
    const float* __restrict__ qs_all, const float* __restrict__ eps,
    float* __restrict__ ws)
{
    const int tid = threadIdx.x, w = tid >> 6, lane = tid & 63;
    const int chunk = blockIdx.x, b = blockIdx.y;
    const int l15 = lane & 15, lg = lane >> 4;
    const int start = B_ * pidx[0];
    const unsigned short* wp = (const unsigned short*)(ws + WS_WP);

    __shared__ unsigned int zu[768];            // 3 tiles * 512 bf16 (frag order)
    __shared__ float sred[8][3][2][16];
    __shared__ float llred[8];

    // ---- stage z fragments into LDS (coalesced eps reads) ----
    if (tid < 384) {
        int m_loc = tid >> 3, l0 = (tid & 7) * 4;
        int m_glob = chunk * 48 + m_loc;
        float4 e = make_float4(0.f, 0.f, 0.f, 0.f);
        if (m_glob < M_) e = *(const float4*)(eps + ((size_t)b * M_ + m_glob) * L_ + l0);
        float4 qm4 = *(const float4*)(qm_all + (size_t)(start + b) * L_ + l0);
        float4 ql4 = *(const float4*)(qlv_all + (size_t)(start + b) * L_ + l0);
        float z0 = qm4.x + __expf(0.5f * ql4.x) * e.x;
        float z1 = qm4.y + __expf(0.5f * ql4.y) * e.y;
        float z2 = qm4.z + __expf(0.5f * ql4.z) * e.z;
        float z3 = qm4.w + __expf(0.5f * ql4.w) * e.w;
        unsigned u0 = (unsigned)f2bf(z0) | ((unsigned)f2bf(z1) << 16);
        unsigned u1 = (unsigned)f2bf(z2) | ((unsigned)f2bf(z3) << 16);
        int idx = (m_loc >> 4) * 256 + (l0 >> 3) * 64 + (m_loc & 15) * 4 + ((l0 & 7) >> 1);
        zu[idx] = u0; zu[idx + 1] = u1;
    }
    __syncthreads();

    // ---- hoisted k-independent constants ----
    const int fr = 4 * lg;
    const int ftA = w, ftB = 8 + w;
    const float* xptr = (w < 4) ? (Xc + b * 64 + w * 16) : (Xb + b * 64 + (w - 4) * 16);
    const float4 xf = *(const float4*)(xptr + fr);
    const int d3 = 2 * w + (lg >> 1);
    const int xd = Xd[b * 16 + d3];
    const int cc0 = 4 * (lg & 1);
    float4 is3;
    is3.x = (cc0 + 0 == xd) ? 1.f : 0.f;  is3.y = (cc0 + 1 == xd) ? 1.f : 0.f;
    is3.z = (cc0 + 2 == xd) ? 1.f : 0.f;  is3.w = (cc0 + 3 == xd) ? 1.f : 0.f;

    const int m0 = chunk * 48 + l15;       // m for mti=0 at this lane
    const bool ok0 = (m0      < M_);
    const bool ok1 = (m0 + 16 < M_);
    const bool ok2 = (m0 + 32 < M_);

    float ta[3] = {0.f, 0.f, 0.f};        // class (t1|t2) per m-tile, k-accumulated
    float tb[3] = {0.f, 0.f, 0.f};        // t3 per m-tile
    float ll = 0.f;

    for (int k = 0; k < K_; ++k) {
        short8v wfA = *(const short8v*)(wp + ((size_t)(k * 16 + ftA)) * 512 + lane * 8);
        short8v wfB = *(const short8v*)(wp + ((size_t)(k * 16 + ftB)) * 512 + lane * 8);
        const float4 biasA = *(const float4*)(ws + WS_BIAS + k * 256 + ftA * 16 + fr);
        const float4 biasB = *(const float4*)(ws + WS_BIAS + k * 256 + ftB * 16 + fr);
        float4 iv4 = make_float4(0.f, 0.f, 0.f, 0.f);
        if (w < 4) iv4 = *(const float4*)(ws + WS_IV + k * 64 + w * 16 + fr);
        const float c1k = (w == 0) ? ws[WS_C1 + k] : 0.f;
        const float qs_k = qs_all[(size_t)(start + b) * K_ + k];

        #pragma unroll
        for (int mti = 0; mti < 3; ++mti) {
            short8v zb = *(const short8v*)((const unsigned short*)zu + mti * 512 + lane * 8);
            f32x4 c0 = {0.f, 0.f, 0.f, 0.f};
            f32x4 c1 = {0.f, 0.f, 0.f, 0.f};
            c0 = __builtin_amdgcn_mfma_f32_16x16x32_bf16(wfA, zb, c0, 0, 0, 0);
            c1 = __builtin_amdgcn_mfma_f32_16x16x32_bf16(wfB, zb, c1, 0, 0, 0);

            float r12;
            if (w < 4) {             // Gaussian
                float s = 0.f, d0;
                d0 = xf.x - (c0[0] + biasA.x); s = fmaf(d0 * d0, iv4.x, s);
                d0 = xf.y - (c0[1] + biasA.y); s = fmaf(d0 * d0, iv4.y, s);
                d0 = xf.z - (c0[2] + biasA.z); s = fmaf(d0 * d0, iv4.z, s);
                d0 = xf.w - (c0[3] + biasA.w); s = fmaf(d0 * d0, iv4.w, s);
                s += __shfl_xor(s, 16, 64); s += __shfl_xor(s, 32, 64);
                r12 = -0.5f * (c1k + s);
            } else {                 // Bernoulli
                float s = 0.f, lgt, sp;
                lgt = c0[0] + biasA.x; sp = fmaxf(lgt, 0.f) + __logf(1.f + __expf(-fabsf(lgt))); s += xf.x * lgt - sp;
                lgt = c0[1] + biasA.y; sp = fmaxf(lgt, 0.f) + __logf(1.f + __expf(-fabsf(lgt))); s += xf.y * lgt - sp;
                lgt = c0[2] + biasA.z; sp = fmaxf(lgt, 0.f) + __logf(1.f + __expf(-fabsf(lgt))); s += xf.z * lgt - sp;
                lgt = c0[3] + biasA.w; sp = fmaxf(lgt, 0.f) + __logf(1.f + __expf(-fabsf(lgt))); s += xf.w * lgt - sp;
                s += __shfl_xor(s, 16, 64); s += __shfl_xor(s, 32, 64);
                r12 = s;
            }

            float r3;
            { float l0v = c1[0] + biasB.x, l1v = c1[1] + biasB.y, l2v = c1[2] + biasB.z, l3v = c1[3] + biasB.w;
              float mx = fmaxf(fmaxf(l0v, l1v), fmaxf(l2v, l3v));
              mx = fmaxf(mx, __shfl_xor(mx, 16, 64));
              float e = __expf(l0v - mx) + __expf(l1v - mx) + __expf(l2v - mx) + __expf(l3v - mx);
              e += __shfl_xor(e, 16, 64);
              float pk = is3.x * l0v + is3.y * l1v + is3.z * l2v + is3.w * l3v;
              pk += __shfl_xor(pk, 16, 64);
              r3 = pk - mx - __logf(e);
              r3 += __shfl_xor(r3, 16, 64); r3 += __shfl_xor(r3, 32, 64);
              r3 *= 0.5f; }

            const bool ok = (mti == 0) ? ok0 : (mti == 1) ? ok1 : ok2;
            if (!ok) { r12 = 0.f; r3 = 0.f; }
            ta[mti] += r12; tb[mti] += r3;
            ll += qs_k * (r12 + r3);
        }
    }

    // ---- LL wave reduce (lanes 0-15 hold per-m totals, duplicated across lg) ----
    ll += __shfl_xor(ll, 1, 64); ll += __shfl_xor(ll, 2, 64);
    ll += __shfl_xor(ll, 4, 64); ll += __shfl_xor(ll, 8, 64);
    if (lane == 0) llred[w] = ll;
    if (lane < 16) {
        #pragma unroll
        for (int mti = 0; mti < 3; ++mti) {
            sred[w][mti][0][l15] = ta[mti];
            sred[w][mti][1][l15] = tb[mti];
        }
    }
    __syncthreads();

    if (tid < 144) {
        int mt = tid / 48, rem = tid % 48, i = rem >> 4, cx = rem & 15;
        float s = 0.f;
        if (i == 0)      { for (int ww = 0; ww < 4; ++ww) s += sred[ww][mt][0][cx]; }
        else if (i == 1) { for (int ww = 4; ww < 8; ++ww) s += sred[ww][mt][0][cx]; }
        else             { for (int ww = 0; ww < 8; ++ww) s += sred[ww][mt][1][cx]; }
        ws[WS_PART + ((size_t)b * 63 + chunk * 3 + mt) * 48 + i * 16 + cx] = s;
    }
    if (tid == 150) {
        float s = 0.f;
        #pragma unroll
        for (int ww = 0; ww < 8; ++ww) s += llred[ww];
        ws[WS_LLP + b * 21 + chunk] = s;
    }
}

// ---------------- final: block 0 = LL/KL/elbo ; blocks 1..12 = term_i[m] ----------------
__global__ __launch_bounds__(256) void mm_final(
    const int* __restrict__ pidx,
    const float* __restrict__ qm_all, const float* __restrict__ qlv_all,
    const float* __restrict__ qs_all,
    const float* __restrict__ pm_all, const float* __restrict__ pv_all,
    const float* __restrict__ pmu_all,
    const float* __restrict__ ws, float* __restrict__ out)
{
    const int tid = threadIdx.x;
    if (blockIdx.x == 0) {
        __shared__ float sdata[256];
        __shared__ float skl[B_], sks[B_];
        const int start = B_ * pidx[0];
        float v = 0.f;
        for (int i = tid; i < 672; i += 256) v += ws[WS_LLP + i];
        sdata[tid] = v;

        if (tid < B_) {
            int r = start + tid;
            float kl = 0.f;
            for (int l = 0; l < L_; ++l) {
                float qmv = qm_all[(size_t)r * L_ + l];
                float qlv = qlv_all[(size_t)r * L_ + l];
                float mp  = pm_all[(size_t)r * L_ + l];
                float vp  = pv_all[(size_t)r * L_ + l];
                float d   = qmv - mp;
                kl += __logf(vp) - qlv + (__expf(qlv) + d * d) / vp - 1.f;
            }
            skl[tid] = 0.5f * kl;

            float qsum = 0.f, psum = 0.f;
            #pragma unroll
            for (int j = 0; j < K_; ++j) {
                qsum += qs_all[(size_t)r * K_ + j];
                psum += pmu_all[(size_t)r * K_ + j];
            }
            float ks = 0.f;
            #pragma unroll
            for (int j = 0; j < K_; ++j) {
                float qn = qs_all[(size_t)r * K_ + j] / qsum;
                float pn = pmu_all[(size_t)r * K_ + j] / psum;
                ks += qn * (__logf(qn) - __logf(pn));
            }
            sks[tid] = ks;
        }
        __syncthreads();
        if (tid == 0) {
            float LL = 0.f;
            for (int i = 0; i < 256; ++i) LL += sdata[i];
            float sklz = 0.f, skls = 0.f;
            for (int i = 0; i < B_; ++i) { sklz += skl[i]; skls += sks[i]; }
            float elbo = LL - sklz - skls;
            out[0] = -elbo;
            out[1] = LL;
            out[2] = skl[B_ - 1];
            out[3] = sks[B_ - 1];
        }
    } else {
        int g = (blockIdx.x - 1) * 256 + tid;
        if (g < 3 * M_) {
            int i = g / M_, m = g % M_;
            int mt = m >> 4, cx = m & 15;
            float s = 0.f;
            #pragma unroll 4
            for (int b2 = 0; b2 < 32; ++b2)
                s += ws[WS_PART + ((size_t)b2 * 63 + mt) * 48 + i * 16 + cx];
            out[OUT_T1 + i * M_ + m] = s;
        }
    }
}

extern "C" void kernel_launch(void* const* d_in, const int* in_sizes, int n_in,
                              void* d_out, int out_size, void* d_ws, size_t ws_size,
                              hipStream_t stream)
{
    (void)in_sizes; (void)n_in; (void)out_size; (void)ws_size;
    const int*   pidx = (const int*)d_in[0];
    const float* Xc   = (const float*)d_in[1];
    const float* Xb   = (const float*)d_in[2];
    const int*   Xd   = (const int*)d_in[3];
    const float* qm   = (const float*)d_in[4];
    const float* qlv  = (const float*)d_in[5];
    const float* qs   = (const float*)d_in[6];
    const float* pm   = (const float*)d_in[7];
    const float* pv   = (const float*)d_in[8];
    const float* pmu  = (const float*)d_in[9];
    const float* Wg   = (const float*)d_in[10];
    const float* bg   = (const float*)d_in[11];
    const float* lvg  = (const float*)d_in[12];
    const float* Wb   = (const float*)d_in[13];
    const float* bb   = (const float*)d_in[14];
    const float* Wd   = (const float*)d_in[15];
    const float* bd   = (const float*)d_in[16];
    const float* eps  = (const float*)d_in[17];
    float* out = (float*)d_out;
    float* ws  = (float*)d_ws;

    mm_prep<<<(PRK + 255) / 256, 256, 0, stream>>>(pidx, qs, Wg, bg, lvg,
                                                   Wb, bb, Wd, bd, out, ws);

    dim3 grid(21, 32);   // (m-chunk of 48 rows, b)
    mm_main<<<grid, 512, 0, stream>>>(pidx, Xc, Xb, Xd, qm, qlv, qs, eps, ws);

    mm_final<<<13, 256, 0, stream>>>(pidx, qm, qlv, qs, pm, pv, pmu, ws, out);
}

// Round 6
// 49.250 us; speedup vs baseline: 2.4545x; 1.0651x over previous
//
#include <hip/hip_runtime.h>
#include <math.h>

#define N_ 4096
#define L_ 32
#define K_ 8
#define Dc_ 64
#define Db_ 64
#define Dd_ 16
#define C_ 8
#define B_ 32
#define M_ 1000
#define LOG2PI_ 1.8378770664093453f

// output layout (floats): [0]=-elbo [1]=LL [2]=KL_z [3]=KL_s
// [4 .. 4+N*K) = rik ; then term_1 (M), term_2 (M), term_3 (M)
#define OUT_RIK 4
#define OUT_T1 (4 + N_ * K_)

// ws float-offsets
#define WS_PART 0                 // 32*63*48 = 96768 floats: per (b,mt) 3x16 (k-summed)
#define WS_LLP  98304             // 2016 floats: per-block LL partials (32 b * 63 mt)
#define WS_WP   100352            // 65536 ushorts (32768 floats): bf16 weight frags
#define WS_BIAS (WS_WP + 32768)   // 2048 floats
#define WS_IV   (WS_BIAS + 2048)  // 512 floats
#define WS_C1   (WS_IV + 512)     // 9 floats: per-k const1 + [8]=total

typedef __attribute__((ext_vector_type(8))) short short8v;
typedef __attribute__((ext_vector_type(4))) float f32x4;

__device__ inline unsigned short f2bf(float f) {
    unsigned u = __builtin_bit_cast(unsigned, f);
    unsigned r = u + 0x7FFFu + ((u >> 16) & 1u);   // round-to-nearest-even
    return (unsigned short)(r >> 16);
}

// ---------------- prep: W-frags, bias/iv/c1, rik ----------------
#define PW  65536
#define PB  (PW + 2048)
#define PIV (PB + 512)
#define PC1 (PIV + 9)
#define PRK (PC1 + N_ * K_)

__global__ __launch_bounds__(256) void mm_prep(
    const int* __restrict__ pidx, const float* __restrict__ qs_all,
    const float* __restrict__ Wg, const float* __restrict__ bg, const float* __restrict__ lvg,
    const float* __restrict__ Wb, const float* __restrict__ bb,
    const float* __restrict__ Wd, const float* __restrict__ bd,
    float* __restrict__ out, float* __restrict__ ws)
{
    const int t = blockIdx.x * 256 + threadIdx.x;
    unsigned short* wpw = (unsigned short*)(ws + WS_WP);

    if (t < PW) {
        // weight fragment elem: [k][ft][lane][j] ; feature = ft*16+(lane&15); l = (lane>>4)*8+j
        int j = t & 7, lane = (t >> 3) & 63, ft = (t >> 9) & 15, k = t >> 13;
        int f = ft * 16 + (lane & 15);
        int l = (lane >> 4) * 8 + j;
        float w;
        if (f < 64)       w = Wg[((size_t)k * 64 + f) * L_ + l];
        else if (f < 128) w = Wb[((size_t)k * 64 + (f - 64)) * L_ + l];
        else { int d = (f - 128) >> 3, c = f & 7; w = Wd[(((size_t)k * 16 + d) * 8 + c) * L_ + l]; }
        wpw[t] = f2bf(w);
    } else if (t < PB) {
        int i = t - PW; int k = i >> 8, f = i & 255;
        float v;
        if (f < 64)       v = bg[k * 64 + f];
        else if (f < 128) v = bb[k * 64 + f - 64];
        else { int d = (f - 128) >> 3, c = f & 7; v = bd[(k * 16 + d) * 8 + c]; }
        ws[WS_BIAS + i] = v;
    } else if (t < PIV) {
        int i = t - PB;
        ws[WS_IV + i] = __expf(-lvg[i]);
    } else if (t < PC1) {
        int k = t - PIV;
        if (k < 8) {
            float s = 0.f;
            for (int d = 0; d < 64; ++d) s += LOG2PI_ + lvg[k * 64 + d];
            ws[WS_C1 + k] = s;
        } else {
            float s = 0.f;
            for (int i = 0; i < 512; ++i) s += LOG2PI_ + lvg[i];
            ws[WS_C1 + 8] = s;
        }
    } else if (t < PRK) {
        int i = t - PC1;
        int r = i / K_, c = i % K_;
        int start = B_ * pidx[0];
        float v = 0.f;
        if (r >= start && r < start + B_) {
            const float* row = qs_all + (size_t)r * K_;
            float mx = row[0];
            #pragma unroll
            for (int jj = 1; jj < K_; ++jj) mx = fmaxf(mx, row[jj]);
            float se = 0.f;
            #pragma unroll
            for (int jj = 0; jj < K_; ++jj) se += __expf(row[jj] - mx);
            v = __expf(row[c] - mx) / se;
        }
        out[OUT_RIK + i] = v;
    }
}

// ---------------- main: grid (63 mt, 32 b); 512 thr = 8 waves ----------------
// One 16-row m-tile per block. Wave w owns feature-tiles {w, 8+w}:
// w<4 -> (t1 tile, t3 tile); w>=4 -> (t2 tile, t3 tile). All reductions deferred
// past the k-loop (only the log-sum-exp pair-combine shuffle stays inside).
__global__ __launch_bounds__(512) void mm_main(
    const int* __restrict__ pidx,
    const float* __restrict__ Xc, const float* __restrict__ Xb, const int* __restrict__ Xd,
    const float* __restrict__ qm_all, const float* __restrict__ qlv_all,
    const float* __restrict__ qs_all, const float* __restrict__ eps,
    float* __restrict__ ws)
{
    const int tid = threadIdx.x, w = tid >> 6, lane = tid & 63;
    const int mt = blockIdx.x, b = blockIdx.y;
    const int l15 = lane & 15, lg = lane >> 4;
    const int start = B_ * pidx[0];
    const unsigned short* wp = (const unsigned short*)(ws + WS_WP);

    __shared__ __align__(16) unsigned int zu[256];   // 512 bf16, frag order
    __shared__ float sred[8][2][16];
    __shared__ float llred[8];

    // ---- stage z fragments into LDS (coalesced eps reads) ----
    if (tid < 128) {
        int m_loc = tid >> 3, l0 = (tid & 7) * 4;
        int m_glob = mt * 16 + m_loc;
        float4 e = make_float4(0.f, 0.f, 0.f, 0.f);
        if (m_glob < M_) e = *(const float4*)(eps + ((size_t)b * M_ + m_glob) * L_ + l0);
        float4 qm4 = *(const float4*)(qm_all + (size_t)(start + b) * L_ + l0);
        float4 ql4 = *(const float4*)(qlv_all + (size_t)(start + b) * L_ + l0);
        float z0 = qm4.x + __expf(0.5f * ql4.x) * e.x;
        float z1 = qm4.y + __expf(0.5f * ql4.y) * e.y;
        float z2 = qm4.z + __expf(0.5f * ql4.z) * e.z;
        float z3 = qm4.w + __expf(0.5f * ql4.w) * e.w;
        unsigned u0 = (unsigned)f2bf(z0) | ((unsigned)f2bf(z1) << 16);
        unsigned u1 = (unsigned)f2bf(z2) | ((unsigned)f2bf(z3) << 16);
        int widx = ((l0 >> 3) * 16 + m_loc) * 4 + ((l0 & 7) >> 1);
        zu[widx] = u0; zu[widx + 1] = u1;
    }
    __syncthreads();

    const short8v zb = *(const short8v*)((const unsigned short*)zu + lane * 8);

    // ---- hoisted k-independent constants ----
    const int fr = 4 * lg;
    const int ftA = w, ftB = 8 + w;
    const float* xptr = (w < 4) ? (Xc + b * 64 + w * 16 + fr) : (Xb + b * 64 + (w - 4) * 16 + fr);
    const float4 xf = *(const float4*)(xptr);
    const int d3 = 2 * w + (lg >> 1);
    const int xd = Xd[b * 16 + d3];
    const int cc0 = 4 * (lg & 1);
    float4 is3;
    is3.x = (cc0 + 0 == xd) ? 1.f : 0.f;  is3.y = (cc0 + 1 == xd) ? 1.f : 0.f;
    is3.z = (cc0 + 2 == xd) ? 1.f : 0.f;  is3.w = (cc0 + 3 == xd) ? 1.f : 0.f;
    const bool ok = (mt * 16 + l15) < M_;

    float ta = 0.f, tb = 0.f, ll = 0.f;

    for (int k = 0; k < K_; ++k) {
        const float qk = qs_all[(size_t)(start + b) * K_ + k];
        const short8v wfA = *(const short8v*)(wp + ((size_t)(k * 16 + ftA)) * 512 + lane * 8);
        const short8v wfB = *(const short8v*)(wp + ((size_t)(k * 16 + ftB)) * 512 + lane * 8);
        const float4 biasA = *(const float4*)(ws + WS_BIAS + k * 256 + ftA * 16 + fr);
        const float4 biasB = *(const float4*)(ws + WS_BIAS + k * 256 + ftB * 16 + fr);

        f32x4 c0 = {0.f, 0.f, 0.f, 0.f};
        f32x4 c1 = {0.f, 0.f, 0.f, 0.f};
        c0 = __builtin_amdgcn_mfma_f32_16x16x32_bf16(wfA, zb, c0, 0, 0, 0);
        c1 = __builtin_amdgcn_mfma_f32_16x16x32_bf16(wfB, zb, c1, 0, 0, 0);

        float sm;
        if (w < 4) {             // Gaussian (per-lane partial over 4 features)
            const float4 iv4 = *(const float4*)(ws + WS_IV + k * 64 + w * 16 + fr);
            float s = 0.f, d0;
            d0 = xf.x - (c0[0] + biasA.x); s = fmaf(d0 * d0, iv4.x, s);
            d0 = xf.y - (c0[1] + biasA.y); s = fmaf(d0 * d0, iv4.y, s);
            d0 = xf.z - (c0[2] + biasA.z); s = fmaf(d0 * d0, iv4.z, s);
            d0 = xf.w - (c0[3] + biasA.w); s = fmaf(d0 * d0, iv4.w, s);
            sm = ok ? s : 0.f;
            float c1t = (w == 0 && lg == 0 && ok) ? ws[WS_C1 + k] : 0.f;
            ll = fmaf(-0.5f * qk, sm + c1t, ll);
        } else {                 // Bernoulli
            float s = 0.f, lgt, sp;
            lgt = c0[0] + biasA.x; sp = fmaxf(lgt, 0.f) + __logf(1.f + __expf(-fabsf(lgt))); s += xf.x * lgt - sp;
            lgt = c0[1] + biasA.y; sp = fmaxf(lgt, 0.f) + __logf(1.f + __expf(-fabsf(lgt))); s += xf.y * lgt - sp;
            lgt = c0[2] + biasA.z; sp = fmaxf(lgt, 0.f) + __logf(1.f + __expf(-fabsf(lgt))); s += xf.z * lgt - sp;
            lgt = c0[3] + biasA.w; sp = fmaxf(lgt, 0.f) + __logf(1.f + __expf(-fabsf(lgt))); s += xf.w * lgt - sp;
            sm = ok ? s : 0.f;
            ll = fmaf(qk, sm, ll);
        }
        ta += sm;

        // categorical: per-lane u (own 4 classes) ; se combined across lg pair
        float l0v = c1[0] + biasB.x, l1v = c1[1] + biasB.y;
        float l2v = c1[2] + biasB.z, l3v = c1[3] + biasB.w;
        float e4 = __expf(l0v) + __expf(l1v) + __expf(l2v) + __expf(l3v);
        float se = e4 + __shfl_xor(e4, 16, 64);
        float u = is3.x * l0v + is3.y * l1v + is3.z * l2v + is3.w * l3v;
        float tm = u - 0.5f * __logf(se);       // log term duplicated on pair -> x0.5
        tm = ok ? tm : 0.f;
        tb += tm;
        ll = fmaf(qk, tm, ll);
    }

    // ---- deferred reductions ----
    float tar = ta + __shfl_xor(ta, 16, 64); tar += __shfl_xor(tar, 32, 64);
    float tbr = tb + __shfl_xor(tb, 16, 64); tbr += __shfl_xor(tbr, 32, 64);
    #pragma unroll
    for (int ofs = 1; ofs < 64; ofs <<= 1) ll += __shfl_xor(ll, ofs, 64);
    if (lane < 16) { sred[w][0][l15] = tar; sred[w][1][l15] = tbr; }
    if (lane == 0) llred[w] = ll;
    __syncthreads();

    if (tid < 48) {
        int i = tid >> 4, cx = tid & 15;
        int m = mt * 16 + cx;
        float vout;
        if (i == 0) {
            float s = sred[0][0][cx] + sred[1][0][cx] + sred[2][0][cx] + sred[3][0][cx];
            vout = (m < M_) ? (-0.5f * (ws[WS_C1 + 8] + s)) : 0.f;
        } else if (i == 1) {
            vout = sred[4][0][cx] + sred[5][0][cx] + sred[6][0][cx] + sred[7][0][cx];
        } else {
            vout = 0.f;
            #pragma unroll
            for (int ww = 0; ww < 8; ++ww) vout += sred[ww][1][cx];
        }
        ws[WS_PART + ((size_t)b * 63 + mt) * 48 + i * 16 + cx] = vout;
    }
    if (tid == 48) {
        float s = 0.f;
        #pragma unroll
        for (int ww = 0; ww < 8; ++ww) s += llred[ww];
        ws[WS_LLP + b * 63 + mt] = s;
    }
}

// ---------------- final: block 0 = LL/KL/elbo ; blocks 1..12 = term_i[m] ----------------
__global__ __launch_bounds__(256) void mm_final(
    const int* __restrict__ pidx,
    const float* __restrict__ qm_all, const float* __restrict__ qlv_all,
    const float* __restrict__ qs_all,
    const float* __restrict__ pm_all, const float* __restrict__ pv_all,
    const float* __restrict__ pmu_all,
    const float* __restrict__ ws, float* __restrict__ out)
{
    const int tid = threadIdx.x;
    if (blockIdx.x == 0) {
        __shared__ float sdata[256];
        __shared__ float skl[B_], sks[B_];
        const int start = B_ * pidx[0];
        float v = 0.f;
        for (int i = tid; i < 2016; i += 256) v += ws[WS_LLP + i];
        sdata[tid] = v;

        if (tid < B_) {
            int r = start + tid;
            float kl = 0.f;
            for (int l = 0; l < L_; ++l) {
                float qmv = qm_all[(size_t)r * L_ + l];
                float qlv = qlv_all[(size_t)r * L_ + l];
                float mp  = pm_all[(size_t)r * L_ + l];
                float vp  = pv_all[(size_t)r * L_ + l];
                float d   = qmv - mp;
                kl += __logf(vp) - qlv + (__expf(qlv) + d * d) / vp - 1.f;
            }
            skl[tid] = 0.5f * kl;

            float qsum = 0.f, psum = 0.f;
            #pragma unroll
            for (int j = 0; j < K_; ++j) {
                qsum += qs_all[(size_t)r * K_ + j];
                psum += pmu_all[(size_t)r * K_ + j];
            }
            float ks = 0.f;
            #pragma unroll
            for (int j = 0; j < K_; ++j) {
                float qn = qs_all[(size_t)r * K_ + j] / qsum;
                float pn = pmu_all[(size_t)r * K_ + j] / psum;
                ks += qn * (__logf(qn) - __logf(pn));
            }
            sks[tid] = ks;
        }
        __syncthreads();
        if (tid == 0) {
            float LL = 0.f;
            for (int i = 0; i < 256; ++i) LL += sdata[i];
            float sklz = 0.f, skls = 0.f;
            for (int i = 0; i < B_; ++i) { sklz += skl[i]; skls += sks[i]; }
            float elbo = LL - sklz - skls;
            out[0] = -elbo;
            out[1] = LL;
            out[2] = skl[B_ - 1];
            out[3] = sks[B_ - 1];
        }
    } else {
        int g = (blockIdx.x - 1) * 256 + tid;
        if (g < 3 * M_) {
            int i = g / M_, m = g % M_;
            int mt = m >> 4, cx = m & 15;
            float s = 0.f;
            #pragma unroll 4
            for (int b2 = 0; b2 < 32; ++b2)
                s += ws[WS_PART + ((size_t)b2 * 63 + mt) * 48 + i * 16 + cx];
            out[OUT_T1 + i * M_ + m] = s;
        }
    }
}

extern "C" void kernel_launch(void* const* d_in, const int* in_sizes, int n_in,
                              void* d_out, int out_size, void* d_ws, size_t ws_size,
                              hipStream_t stream)
{
    (void)in_sizes; (void)n_in; (void)out_size; (void)ws_size;
    const int*   pidx = (const int*)d_in[0];
    const float* Xc   = (const float*)d_in[1];
    const float* Xb   = (const float*)d_in[2];
    const int*   Xd   = (const int*)d_in[3];
    const float* qm   = (const float*)d_in[4];
    const float* qlv  = (const float*)d_in[5];
    const float* qs   = (const float*)d_in[6];
    const float* pm   = (const float*)d_in[7];
    const float* pv   = (const float*)d_in[8];
    const float* pmu  = (const float*)d_in[9];
    const float* Wg   = (const float*)d_in[10];
    const float* bg   = (const float*)d_in[11];
    const float* lvg  = (const float*)d_in[12];
    const float* Wb   = (const float*)d_in[13];
    const float* bb   = (const float*)d_in[14];
    const float* Wd   = (const float*)d_in[15];
    const float* bd   = (const float*)d_in[16];
    const float* eps  = (const float*)d_in[17];
    float* out = (float*)d_out;
    float* ws  = (float*)d_ws;

    mm_prep<<<(PRK + 255) / 256, 256, 0, stream>>>(pidx, qs, Wg, bg, lvg,
                                                   Wb, bb, Wd, bd, out, ws);

    dim3 grid(63, 32);   // (m-tile of 16 rows, b)
    mm_main<<<grid, 512, 0, stream>>>(pidx, Xc, Xb, Xd, qm, qlv, qs, eps, ws);

    mm_final<<<13, 256, 0, stream>>>(pidx, qm, qlv, qs, pm, pv, pmu, ws, out);
}

// Round 7
// 42.245 us; speedup vs baseline: 2.8615x; 1.1658x over previous
//
#include <hip/hip_runtime.h>
#include <math.h>

#define N_ 4096
#define L_ 32
#define K_ 8
#define Dc_ 64
#define Db_ 64
#define Dd_ 16
#define C_ 8
#define B_ 32
#define M_ 1000
#define LOG2PI_ 1.8378770664093453f

// output layout (floats): [0]=-elbo [1]=LL [2]=KL_z [3]=KL_s
// [4 .. 4+N*K) = rik ; then term_1 (M), term_2 (M), term_3 (M)
#define OUT_RIK 4
#define OUT_T1 (4 + N_ * K_)

// ws float-offsets
#define WS_PART 0                 // 32*64*48 = 98304 floats: per (b, rt) 3x16 (k-summed)
#define WS_LLP  98304             // 1024 floats: per-block LL partials (32 b * 32 mt)
#define WS_WP   99328             // 65536 ushorts (32768 floats): bf16 weight frags
#define WS_BIAS (WS_WP + 32768)   // 2048 floats (raw bias per (k,f))
#define WS_IV   (WS_BIAS + 2048)  // 512 floats
#define WS_C1   (WS_IV + 512)     // 9 floats: per-k const1 + [8]=total

typedef __attribute__((ext_vector_type(8))) short short8v;
typedef __attribute__((ext_vector_type(4))) float f32x4;

__device__ inline unsigned short f2bf(float f) {
    unsigned u = __builtin_bit_cast(unsigned, f);
    unsigned r = u + 0x7FFFu + ((u >> 16) & 1u);   // round-to-nearest-even
    return (unsigned short)(r >> 16);
}

// ---------------- prep: W-frags, bias/iv/c1 ----------------
#define PW  65536
#define PB  (PW + 2048)
#define PIV (PB + 512)
#define PC1 (PIV + 9)

__global__ __launch_bounds__(256) void mm_prep(
    const float* __restrict__ Wg, const float* __restrict__ bg, const float* __restrict__ lvg,
    const float* __restrict__ Wb, const float* __restrict__ bb,
    const float* __restrict__ Wd, const float* __restrict__ bd,
    float* __restrict__ ws)
{
    const int t = blockIdx.x * 256 + threadIdx.x;
    unsigned short* wpw = (unsigned short*)(ws + WS_WP);

    if (t < PW) {
        // weight fragment elem: [k][ft][lane][j] ; feature = ft*16+(lane&15); l = (lane>>4)*8+j
        int j = t & 7, lane = (t >> 3) & 63, ft = (t >> 9) & 15, k = t >> 13;
        int f = ft * 16 + (lane & 15);
        int l = (lane >> 4) * 8 + j;
        float w;
        if (f < 64)       w = Wg[((size_t)k * 64 + f) * L_ + l];
        else if (f < 128) w = Wb[((size_t)k * 64 + (f - 64)) * L_ + l];
        else { int d = (f - 128) >> 3, c = f & 7; w = Wd[(((size_t)k * 16 + d) * 8 + c) * L_ + l]; }
        wpw[t] = f2bf(w);
    } else if (t < PB) {
        int i = t - PW; int k = i >> 8, f = i & 255;
        float v;
        if (f < 64)       v = bg[k * 64 + f];
        else if (f < 128) v = bb[k * 64 + f - 64];
        else { int d = (f - 128) >> 3, c = f & 7; v = bd[(k * 16 + d) * 8 + c]; }
        ws[WS_BIAS + i] = v;
    } else if (t < PIV) {
        int i = t - PB;
        ws[WS_IV + i] = __expf(-lvg[i]);
    } else if (t < PC1) {
        int k = t - PIV;
        if (k < 8) {
            float s = 0.f;
            for (int d = 0; d < 64; ++d) s += LOG2PI_ + lvg[k * 64 + d];
            ws[WS_C1 + k] = s;
        } else {
            float s = 0.f;
            for (int i = 0; i < 512; ++i) s += LOG2PI_ + lvg[i];
            ws[WS_C1 + 8] = s;
        }
    }
}

// ---------------- main: grid (32 mt, 32 b); 512 thr = 8 waves ----------------
// Two 16-row m-tiles per block. Wave w owns feature-tiles {w, 8+w}.
// Bias (minus Xc for Gaussian) folded into the MFMA C operand; bias/iv/qs staged
// in LDS; all masking and the Gaussian const term deferred out of the k-loop.
__global__ __launch_bounds__(512) void mm_main(
    const int* __restrict__ pidx,
    const float* __restrict__ Xc, const float* __restrict__ Xb, const int* __restrict__ Xd,
    const float* __restrict__ qm_all, const float* __restrict__ qlv_all,
    const float* __restrict__ qs_all, const float* __restrict__ eps,
    float* __restrict__ ws)
{
    const int tid = threadIdx.x, w = tid >> 6, lane = tid & 63;
    const int mt = blockIdx.x, b = blockIdx.y;
    const int l15 = lane & 15, lg = lane >> 4;
    const int fr = 4 * lg;
    const int start = B_ * pidx[0];
    const unsigned short* wp = (const unsigned short*)(ws + WS_WP);

    __shared__ __align__(16) unsigned int zu[512];     // 2 tiles * 512 bf16
    __shared__ __align__(16) float scin[2048];         // bias (-Xc for f<64) per (k,f)
    __shared__ __align__(16) float siv[512];
    __shared__ float sqk[8];
    __shared__ float sred[8][2][2][16];
    __shared__ float llred[8];

    // ---- stage z fragments (256 thr), cinit (512 thr), iv (128 thr), qs (8 thr) ----
    if (tid < 256) {
        int m_loc = tid >> 3, l0 = (tid & 7) * 4;
        int m_glob = mt * 32 + m_loc;
        float4 e = make_float4(0.f, 0.f, 0.f, 0.f);
        if (m_glob < M_) e = *(const float4*)(eps + ((size_t)b * M_ + m_glob) * L_ + l0);
        float4 qm4 = *(const float4*)(qm_all + (size_t)(start + b) * L_ + l0);
        float4 ql4 = *(const float4*)(qlv_all + (size_t)(start + b) * L_ + l0);
        float z0 = qm4.x + __expf(0.5f * ql4.x) * e.x;
        float z1 = qm4.y + __expf(0.5f * ql4.y) * e.y;
        float z2 = qm4.z + __expf(0.5f * ql4.z) * e.z;
        float z3 = qm4.w + __expf(0.5f * ql4.w) * e.w;
        unsigned u0 = (unsigned)f2bf(z0) | ((unsigned)f2bf(z1) << 16);
        unsigned u1 = (unsigned)f2bf(z2) | ((unsigned)f2bf(z3) << 16);
        int widx = (m_loc >> 4) * 256 + ((l0 >> 3) * 16 + (m_loc & 15)) * 4 + ((l0 & 7) >> 1);
        zu[widx] = u0; zu[widx + 1] = u1;
    }
    {   // cinit: k = tid>>6, f = (tid&63)*4
        int f = (tid & 63) * 4;
        float4 bv = *(const float4*)(ws + WS_BIAS + tid * 4);
        if (f < 64) {
            float4 xc = *(const float4*)(Xc + b * 64 + f);
            bv.x -= xc.x; bv.y -= xc.y; bv.z -= xc.z; bv.w -= xc.w;
        }
        ((float4*)scin)[tid] = bv;
    }
    if (tid < 128) ((float4*)siv)[tid] = *(const float4*)(ws + WS_IV + tid * 4);
    if (tid < 8)   sqk[tid] = qs_all[(size_t)(start + b) * K_ + tid];
    __syncthreads();

    const short8v zb0 = *(const short8v*)((const unsigned short*)zu + lane * 8);
    const short8v zb1 = *(const short8v*)((const unsigned short*)zu + 512 + lane * 8);

    // ---- hoisted constants ----
    const float4 xf = *(const float4*)(Xb + b * 64 + (w & 3) * 16 + fr);  // used when w>=4
    const int d3 = 2 * w + (lg >> 1);
    const int xd = Xd[b * 16 + d3];
    const int cc0 = 4 * (lg & 1);
    float4 is3;
    is3.x = (cc0 + 0 == xd) ? 1.f : 0.f;  is3.y = (cc0 + 1 == xd) ? 1.f : 0.f;
    is3.z = (cc0 + 2 == xd) ? 1.f : 0.f;  is3.w = (cc0 + 3 == xd) ? 1.f : 0.f;

    float ta0 = 0.f, ta1 = 0.f, tb0 = 0.f, tb1 = 0.f, ll0 = 0.f, ll1 = 0.f;

    #pragma unroll 2
    for (int k = 0; k < K_; ++k) {
        const short8v wfA = *(const short8v*)(wp + ((size_t)(k * 16 + w))     * 512 + lane * 8);
        const short8v wfB = *(const short8v*)(wp + ((size_t)(k * 16 + 8 + w)) * 512 + lane * 8);
        const float4 cA = *(const float4*)(scin + k * 256 + w * 16 + fr);
        const float4 cB = *(const float4*)(scin + k * 256 + (8 + w) * 16 + fr);
        const float qkv = sqk[k];

        const f32x4 ciA = {cA.x, cA.y, cA.z, cA.w};
        const f32x4 ciB = {cB.x, cB.y, cB.z, cB.w};
        f32x4 d00 = __builtin_amdgcn_mfma_f32_16x16x32_bf16(wfA, zb0, ciA, 0, 0, 0);
        f32x4 d01 = __builtin_amdgcn_mfma_f32_16x16x32_bf16(wfA, zb1, ciA, 0, 0, 0);
        f32x4 d10 = __builtin_amdgcn_mfma_f32_16x16x32_bf16(wfB, zb0, ciB, 0, 0, 0);
        f32x4 d11 = __builtin_amdgcn_mfma_f32_16x16x32_bf16(wfB, zb1, ciB, 0, 0, 0);

        if (w < 4) {             // Gaussian: d = (mean+bias-x) already
            const float4 iv4 = *(const float4*)(siv + k * 64 + w * 16 + fr);
            float s0 = 0.f, s1 = 0.f;
            s0 = fmaf(d00[0] * d00[0], iv4.x, s0); s1 = fmaf(d01[0] * d01[0], iv4.x, s1);
            s0 = fmaf(d00[1] * d00[1], iv4.y, s0); s1 = fmaf(d01[1] * d01[1], iv4.y, s1);
            s0 = fmaf(d00[2] * d00[2], iv4.z, s0); s1 = fmaf(d01[2] * d01[2], iv4.z, s1);
            s0 = fmaf(d00[3] * d00[3], iv4.w, s0); s1 = fmaf(d01[3] * d01[3], iv4.w, s1);
            ta0 += s0; ta1 += s1;
            const float qm5 = -0.5f * qkv;
            ll0 = fmaf(qm5, s0, ll0); ll1 = fmaf(qm5, s1, ll1);
        } else {                 // Bernoulli
            float s0 = 0.f, s1 = 0.f, lgt, sp;
            lgt = d00[0]; sp = fmaxf(lgt, 0.f) + __logf(1.f + __expf(-fabsf(lgt))); s0 += xf.x * lgt - sp;
            lgt = d00[1]; sp = fmaxf(lgt, 0.f) + __logf(1.f + __expf(-fabsf(lgt))); s0 += xf.y * lgt - sp;
            lgt = d00[2]; sp = fmaxf(lgt, 0.f) + __logf(1.f + __expf(-fabsf(lgt))); s0 += xf.z * lgt - sp;
            lgt = d00[3]; sp = fmaxf(lgt, 0.f) + __logf(1.f + __expf(-fabsf(lgt))); s0 += xf.w * lgt - sp;
            lgt = d01[0]; sp = fmaxf(lgt, 0.f) + __logf(1.f + __expf(-fabsf(lgt))); s1 += xf.x * lgt - sp;
            lgt = d01[1]; sp = fmaxf(lgt, 0.f) + __logf(1.f + __expf(-fabsf(lgt))); s1 += xf.y * lgt - sp;
            lgt = d01[2]; sp = fmaxf(lgt, 0.f) + __logf(1.f + __expf(-fabsf(lgt))); s1 += xf.z * lgt - sp;
            lgt = d01[3]; sp = fmaxf(lgt, 0.f) + __logf(1.f + __expf(-fabsf(lgt))); s1 += xf.w * lgt - sp;
            ta0 += s0; ta1 += s1;
            ll0 = fmaf(qkv, s0, ll0); ll1 = fmaf(qkv, s1, ll1);
        }

        // categorical tile (all waves)
        {
            float e4 = __expf(d10[0]) + __expf(d10[1]) + __expf(d10[2]) + __expf(d10[3]);
            float se = e4 + __shfl_xor(e4, 16, 64);
            float u  = is3.x * d10[0] + is3.y * d10[1] + is3.z * d10[2] + is3.w * d10[3];
            float tm = u - 0.5f * __logf(se);
            tb0 += tm; ll0 = fmaf(qkv, tm, ll0);
        }
        {
            float e4 = __expf(d11[0]) + __expf(d11[1]) + __expf(d11[2]) + __expf(d11[3]);
            float se = e4 + __shfl_xor(e4, 16, 64);
            float u  = is3.x * d11[0] + is3.y * d11[1] + is3.z * d11[2] + is3.w * d11[3];
            float tm = u - 0.5f * __logf(se);
            tb1 += tm; ll1 = fmaf(qkv, tm, ll1);
        }
    }

    // ---- deferred masking + reductions ----
    const bool ok0 = (mt * 32 + l15)      < M_;
    const bool ok1 = (mt * 32 + 16 + l15) < M_;
    if (!ok0) { ta0 = 0.f; tb0 = 0.f; ll0 = 0.f; }
    if (!ok1) { ta1 = 0.f; tb1 = 0.f; ll1 = 0.f; }

    float tar0 = ta0 + __shfl_xor(ta0, 16, 64); tar0 += __shfl_xor(tar0, 32, 64);
    float tar1 = ta1 + __shfl_xor(ta1, 16, 64); tar1 += __shfl_xor(tar1, 32, 64);
    float tbr0 = tb0 + __shfl_xor(tb0, 16, 64); tbr0 += __shfl_xor(tbr0, 32, 64);
    float tbr1 = tb1 + __shfl_xor(tb1, 16, 64); tbr1 += __shfl_xor(tbr1, 32, 64);
    float llv = ll0 + ll1;
    #pragma unroll
    for (int ofs = 1; ofs < 64; ofs <<= 1) llv += __shfl_xor(llv, ofs, 64);

    if (lane < 16) {
        sred[w][0][0][l15] = tar0; sred[w][1][0][l15] = tar1;
        sred[w][0][1][l15] = tbr0; sred[w][1][1][l15] = tbr1;
    }
    if (lane == 0) llred[w] = llv;
    __syncthreads();

    if (tid < 96) {
        int i = tid >> 5, tile = (tid >> 4) & 1, cx = tid & 15;
        int rt = mt * 2 + tile, m = rt * 16 + cx;
        float vout;
        if (i == 0) {
            float s = sred[0][tile][0][cx] + sred[1][tile][0][cx]
                    + sred[2][tile][0][cx] + sred[3][tile][0][cx];
            vout = (m < M_) ? (-0.5f * (ws[WS_C1 + 8] + s)) : 0.f;
        } else if (i == 1) {
            vout = sred[4][tile][0][cx] + sred[5][tile][0][cx]
                 + sred[6][tile][0][cx] + sred[7][tile][0][cx];
        } else {
            vout = 0.f;
            #pragma unroll
            for (int ww = 0; ww < 8; ++ww) vout += sred[ww][tile][1][cx];
        }
        ws[WS_PART + ((size_t)b * 64 + rt) * 48 + i * 16 + cx] = vout;
    }
    if (tid == 96) {
        float s = 0.f;
        #pragma unroll
        for (int ww = 0; ww < 8; ++ww) s += llred[ww];
        float cterm = 0.f;
        #pragma unroll
        for (int k = 0; k < 8; ++k) cterm = fmaf(sqk[k], ws[WS_C1 + k], cterm);
        int nv = M_ - mt * 32; nv = (nv > 32) ? 32 : (nv < 0 ? 0 : nv);
        ws[WS_LLP + b * 32 + mt] = s - 0.5f * cterm * (float)nv;
    }
}

// ---------------- final: block 0 = LL/KL/elbo ; 1..12 = terms ; 13..140 = rik ----------------
__global__ __launch_bounds__(256) void mm_final(
    const int* __restrict__ pidx,
    const float* __restrict__ qm_all, const float* __restrict__ qlv_all,
    const float* __restrict__ qs_all,
    const float* __restrict__ pm_all, const float* __restrict__ pv_all,
    const float* __restrict__ pmu_all,
    const float* __restrict__ ws, float* __restrict__ out)
{
    const int tid = threadIdx.x;
    if (blockIdx.x == 0) {
        __shared__ float wred[4];
        __shared__ float skl[B_], sks[B_];
        const int start = B_ * pidx[0];
        float v = ws[WS_LLP + tid] + ws[WS_LLP + 256 + tid]
                + ws[WS_LLP + 512 + tid] + ws[WS_LLP + 768 + tid];
        #pragma unroll
        for (int ofs = 1; ofs < 64; ofs <<= 1) v += __shfl_xor(v, ofs, 64);
        if ((tid & 63) == 0) wred[tid >> 6] = v;

        if (tid < B_) {
            int r = start + tid;
            float kl = 0.f;
            for (int l = 0; l < L_; ++l) {
                float qmv = qm_all[(size_t)r * L_ + l];
                float qlv = qlv_all[(size_t)r * L_ + l];
                float mp  = pm_all[(size_t)r * L_ + l];
                float vp  = pv_all[(size_t)r * L_ + l];
                float d   = qmv - mp;
                kl += __logf(vp) - qlv + (__expf(qlv) + d * d) / vp - 1.f;
            }
            skl[tid] = 0.5f * kl;

            float qsum = 0.f, psum = 0.f;
            #pragma unroll
            for (int j = 0; j < K_; ++j) {
                qsum += qs_all[(size_t)r * K_ + j];
                psum += pmu_all[(size_t)r * K_ + j];
            }
            float ks = 0.f;
            #pragma unroll
            for (int j = 0; j < K_; ++j) {
                float qn = qs_all[(size_t)r * K_ + j] / qsum;
                float pn = pmu_all[(size_t)r * K_ + j] / psum;
                ks += qn * (__logf(qn) - __logf(pn));
            }
            sks[tid] = ks;
        }
        __syncthreads();
        if (tid == 0) {
            float LL = wred[0] + wred[1] + wred[2] + wred[3];
            float sklz = 0.f, skls = 0.f;
            for (int i = 0; i < B_; ++i) { sklz += skl[i]; skls += sks[i]; }
            float elbo = LL - sklz - skls;
            out[0] = -elbo;
            out[1] = LL;
            out[2] = skl[B_ - 1];
            out[3] = sks[B_ - 1];
        }
    } else if (blockIdx.x <= 12) {
        int g = (blockIdx.x - 1) * 256 + tid;
        if (g < 3 * M_) {
            int i = g / M_, m = g % M_;
            int rt = m >> 4, cx = m & 15;
            float s = 0.f;
            #pragma unroll 8
            for (int b2 = 0; b2 < 32; ++b2)
                s += ws[WS_PART + ((size_t)b2 * 64 + rt) * 48 + i * 16 + cx];
            out[OUT_T1 + i * M_ + m] = s;
        }
    } else {
        int i = (blockIdx.x - 13) * 256 + tid;   // [0, N*K)
        int r = i >> 3, c = i & 7;
        int start = B_ * pidx[0];
        float v = 0.f;
        if (r >= start && r < start + B_) {
            const float* row = qs_all + (size_t)r * K_;
            float mx = row[0];
            #pragma unroll
            for (int jj = 1; jj < K_; ++jj) mx = fmaxf(mx, row[jj]);
            float se = 0.f;
            #pragma unroll
            for (int jj = 0; jj < K_; ++jj) se += __expf(row[jj] - mx);
            v = __expf(row[c] - mx) / se;
        }
        out[OUT_RIK + i] = v;
    }
}

extern "C" void kernel_launch(void* const* d_in, const int* in_sizes, int n_in,
                              void* d_out, int out_size, void* d_ws, size_t ws_size,
                              hipStream_t stream)
{
    (void)in_sizes; (void)n_in; (void)out_size; (void)ws_size;
    const int*   pidx = (const int*)d_in[0];
    const float* Xc   = (const float*)d_in[1];
    const float* Xb   = (const float*)d_in[2];
    const int*   Xd   = (const int*)d_in[3];
    const float* qm   = (const float*)d_in[4];
    const float* qlv  = (const float*)d_in[5];
    const float* qs   = (const float*)d_in[6];
    const float* pm   = (const float*)d_in[7];
    const float* pv   = (const float*)d_in[8];
    const float* pmu  = (const float*)d_in[9];
    const float* Wg   = (const float*)d_in[10];
    const float* bg   = (const float*)d_in[11];
    const float* lvg  = (const float*)d_in[12];
    const float* Wb   = (const float*)d_in[13];
    const float* bb   = (const float*)d_in[14];
    const float* Wd   = (const float*)d_in[15];
    const float* bd   = (const float*)d_in[16];
    const float* eps  = (const float*)d_in[17];
    float* out = (float*)d_out;
    float* ws  = (float*)d_ws;

    mm_prep<<<(PC1 + 255) / 256, 256, 0, stream>>>(Wg, bg, lvg, Wb, bb, Wd, bd, ws);

    dim3 grid(32, 32);   // (m-tile-pair of 32 rows, b)
    mm_main<<<grid, 512, 0, stream>>>(pidx, Xc, Xb, Xd, qm, qlv, qs, eps, ws);

    mm_final<<<141, 256, 0, stream>>>(pidx, qm, qlv, qs, pm, pv, pmu, ws, out);
}